// Round 3
// baseline (447.580 us; speedup 1.0000x reference)
//
#include <hip/hip_runtime.h>
#include <hip/hip_cooperative_groups.h>

namespace cg = cooperative_groups;

typedef unsigned short u16;

#define NGRAPH 16
#define SEQ    1024
#define DIM    128
#define NHEAD  2
#define HDIM   64
#define KPOS   20
#define NTOT   (NGRAPH*SEQ)     // 16384
#define QKVD   (3*DIM)          // 384

// ---------- bf16 helpers ----------------------------------------------------
__device__ __forceinline__ float bf2f(u16 u) {
    return __uint_as_float(((unsigned int)u) << 16);
}
__device__ __forceinline__ u16 f2bf(float f) {
    unsigned int u = __float_as_uint(f);
    u += 0x7fffu + ((u >> 16) & 1u);   // RNE
    return (u16)(u >> 16);
}

// ---------- DPP 16-lane reductions (VALU, keeps DS pipe free) --------------
template<int CTRL>
__device__ __forceinline__ float dpp_ror(float x) {
    return __int_as_float(__builtin_amdgcn_update_dpp(
        __float_as_int(x), __float_as_int(x), CTRL, 0xF, 0xF, true));
}
__device__ __forceinline__ float row16_max(float x) {
    x = fmaxf(x, dpp_ror<0x121>(x));
    x = fmaxf(x, dpp_ror<0x122>(x));
    x = fmaxf(x, dpp_ror<0x124>(x));
    x = fmaxf(x, dpp_ror<0x128>(x));
    return x;
}
__device__ __forceinline__ float row16_sum(float x) {
    x += dpp_ror<0x121>(x);
    x += dpp_ror<0x122>(x);
    x += dpp_ror<0x124>(x);
    x += dpp_ror<0x128>(x);
    return x;
}

// ---------- dtype-adaptive input loads (fbf=1: bf16, fbf=0: f32) -----------
__device__ __forceinline__ float ld1(const void* p, int fbf, size_t i) {
    return fbf ? bf2f(((const u16*)p)[i]) : ((const float*)p)[i];
}
__device__ __forceinline__ float4 ldw8(const void* W, int fbf, size_t i) {
    if (fbf) return *(const float4*)((const u16*)W + i);
    const float* q = (const float*)W + i;
    float4 a = *(const float4*)q, b = *(const float4*)(q + 4);
    float4 r;
    u16* d = (u16*)&r;
    d[0]=f2bf(a.x); d[1]=f2bf(a.y); d[2]=f2bf(a.z); d[3]=f2bf(a.w);
    d[4]=f2bf(b.x); d[5]=f2bf(b.y); d[6]=f2bf(b.z); d[7]=f2bf(b.w);
    return r;
}

typedef __attribute__((ext_vector_type(8))) short bf16x8;
typedef __attribute__((ext_vector_type(4))) float f32x4;

// ============================================================================
//                    FUSED COOPERATIVE SINGLE-KERNEL PATH
// R2 post-mortem: every kernel <10% on every pipe, and a ~1.6-GFLOP GEMM
// (mgemm<0,1>) measures 45 us == attn's 45 us despite 5x less work; pe with
// 8192 blocks is fast. => fixed per-dispatch cost (launch gaps / ramp)
// dominates the 7-kernel pipeline. Fix: one persistent cooperative kernel,
// phases separated by grid.sync(). GEMM re-tiled to 64x128-out with split-W
// staging so LDS union = attn's 36864 B -> 4 blocks/CU co-resident.
// ============================================================================

#define SMEM_BYTES 36864

struct FArgs {
    const void *x, *pos, *pe_w, *pe_b, *in_w, *in_b, *out_w, *out_b;
    const void *ln1_g, *ln1_b, *ln2_g, *ln2_b, *ff1_w, *ff1_b, *ff2_w, *ff2_b;
    u16* h01;        // h0/h1 slots (= d_out buffer)
    u16* qkv;        // ws [0,12M)
    u16* ctx;        // ws [12M,16M)
    u16* f1;         // ws [0,16M) reuse
    void* dout;      // final output
    int* flag;
};

// ---- GEMM tile: 64 rows x 128 cols, K = NK*128, split-W (two 64-col halves)
// LDS: Ash 64x136 + Wsh 64x136 = 34816 B. Epilogue identical to old mgemm.
template<int EPI, int NK>
__device__ __forceinline__ void gemm_tile(
    const u16* __restrict__ A, const void* __restrict__ W,
    const void* __restrict__ bias, const u16* __restrict__ resid,
    const void* __restrict__ lng, const void* __restrict__ lnb,
    void* __restrict__ outp, int Mtot, int Astr, int arow0, int orow0,
    int n0, int m0, int fbf, int rs, char* smem)
{
    u16 (*Ash)[136] = (u16(*)[136])smem;
    u16 (*Wsh)[136] = (u16(*)[136])(smem + 17408);
    const int K = NK * 128;
    int t = threadIdx.x;
    int w = t >> 6, lane = t & 63, l16 = lane & 15, quad = lane >> 4;
    __syncthreads();   // protect LDS reuse across consecutive tiles/phases
    f32x4 acc[8] = {};
    float4 aR[4], wR[4];
#pragma unroll
    for (int i = 0; i < 4; ++i) {
        int idx = t + i * 256, r2 = idx >> 4, k8 = (idx & 15) * 8;
        aR[i] = *(const float4*)&A[(size_t)(arow0 + n0 + r2) * Astr + k8];
        wR[i] = ldw8(W, fbf, (size_t)(m0 + r2) * K + k8);
    }
#pragma unroll 1
    for (int c = 0; c < NK; ++c) {
#pragma unroll
        for (int i = 0; i < 4; ++i) {
            int idx = t + i * 256, r2 = idx >> 4, k8 = (idx & 15) * 8;
            *(float4*)&Ash[r2][k8] = aR[i];
            *(float4*)&Wsh[r2][k8] = wR[i];
        }
        __syncthreads();
        // prefetch W half-1 (cols m0+64..m0+127) of this chunk
#pragma unroll
        for (int i = 0; i < 4; ++i) {
            int idx = t + i * 256, r2 = idx >> 4, k8 = (idx & 15) * 8;
            wR[i] = ldw8(W, fbf, (size_t)(m0 + 64 + r2) * K + c * 128 + k8);
        }
        bf16x8 af[4];
        __builtin_amdgcn_s_setprio(1);
#pragma unroll
        for (int kk = 0; kk < 4; ++kk) {
            af[kk] = *(const bf16x8*)&Ash[w * 16 + l16][kk * 32 + quad * 8];
#pragma unroll
            for (int s = 0; s < 4; ++s) {
                bf16x8 bf = *(const bf16x8*)&Wsh[s * 16 + l16][kk * 32 + quad * 8];
                acc[s] = __builtin_amdgcn_mfma_f32_16x16x32_bf16(af[kk], bf, acc[s], 0, 0, 0);
            }
        }
        __builtin_amdgcn_s_setprio(0);
        __syncthreads();   // Wsh half-0 consumed
#pragma unroll
        for (int i = 0; i < 4; ++i) {
            int idx = t + i * 256, r2 = idx >> 4, k8 = (idx & 15) * 8;
            *(float4*)&Wsh[r2][k8] = wR[i];
        }
        __syncthreads();
        if (c + 1 < NK) {  // prefetch next chunk A + W half-0 (overlaps MFMA)
#pragma unroll
            for (int i = 0; i < 4; ++i) {
                int idx = t + i * 256, r2 = idx >> 4, k8 = (idx & 15) * 8;
                aR[i] = *(const float4*)&A[(size_t)(arow0 + n0 + r2) * Astr + (c + 1) * 128 + k8];
                wR[i] = ldw8(W, fbf, (size_t)(m0 + r2) * K + (c + 1) * 128 + k8);
            }
        }
        __builtin_amdgcn_s_setprio(1);
#pragma unroll
        for (int kk = 0; kk < 4; ++kk) {
#pragma unroll
            for (int s = 0; s < 4; ++s) {
                bf16x8 bf = *(const bf16x8*)&Wsh[s * 16 + l16][kk * 32 + quad * 8];
                acc[4 + s] = __builtin_amdgcn_mfma_f32_16x16x32_bf16(af[kk], bf, acc[4 + s], 0, 0, 0);
            }
        }
        __builtin_amdgcn_s_setprio(0);
        if (c + 1 < NK) __syncthreads();
    }
    // ---- epilogue (identical semantics to old mgemm) ----
    float bb[8];
#pragma unroll
    for (int s = 0; s < 8; ++s) bb[s] = ld1(bias, fbf, m0 + s * 16 + l16);
    float gg[8], be[8];
    if (EPI >= 2) {
#pragma unroll
        for (int s = 0; s < 8; ++s) {
            gg[s] = ld1(lng, fbf, s * 16 + l16);
            be[s] = ld1(lnb, fbf, s * 16 + l16);
        }
    }
#pragma unroll
    for (int r = 0; r < 4; ++r) {
        int lr = w * 16 + quad * 4 + r;
        float v[8];
#pragma unroll
        for (int s = 0; s < 8; ++s) {
            v[s] = acc[s][r] + bb[s];
            if (EPI == 1) v[s] = fmaxf(v[s], 0.f);
        }
        if (EPI <= 1) {
            u16* o = (u16*)outp;
#pragma unroll
            for (int s = 0; s < 8; ++s)
                o[(size_t)(n0 + lr) * Mtot + m0 + s * 16 + l16] = f2bf(v[s]);
        } else {
            size_t rg = (size_t)(orow0 + n0 + lr);
#pragma unroll
            for (int s = 0; s < 8; ++s)
                v[s] += bf2f(resid[rg * rs + s * 16 + l16]);
            float sm = 0.f, sq = 0.f;
#pragma unroll
            for (int s = 0; s < 8; ++s) { sm += v[s]; sq += v[s] * v[s]; }
            sm = row16_sum(sm);
            sq = row16_sum(sq);
            float mu  = sm * (1.f / DIM);
            float var = fmaxf(sq * (1.f / DIM) - mu * mu, 0.f);
            float rsq = rsqrtf(var + 1e-5f);
            if (EPI == 2) {
                u16* o = (u16*)outp;
#pragma unroll
                for (int s = 0; s < 8; ++s)
                    o[rg * rs + s * 16 + l16] =
                        f2bf((v[s] - mu) * rsq * gg[s] + be[s]);
            } else {
                if (fbf) {
                    u16* o = (u16*)outp;
#pragma unroll
                    for (int s = 0; s < 8; ++s)
                        o[rg * 128 + s * 16 + l16] =
                            f2bf((v[s] - mu) * rsq * gg[s] + be[s]);
                } else {
                    float* o = (float*)outp;
#pragma unroll
                    for (int s = 0; s < 8; ++s)
                        o[rg * 128 + s * 16 + l16] =
                            (v[s] - mu) * rsq * gg[s] + be[s];
                }
            }
        }
    }
}

// ---- attention tile (one (graph,head,q-tile) item), 256 threads -----------
__device__ __forceinline__ void attn_tile(const u16* __restrict__ qkv,
                                          u16* __restrict__ ctx,
                                          int it, char* smem)
{
    u16 (*Qsh)[72]  = (u16(*)[72])(smem);
    u16 (*Ksh)[72]  = (u16(*)[72])(smem +  9216);
    u16 (*VshT)[72] = (u16(*)[72])(smem + 18432);
    u16 (*Psh)[72]  = (u16(*)[72])(smem + 27648);
    int t    = threadIdx.x;
    int w    = t >> 6;
    int lane = t & 63;
    int l16  = lane & 15;
    int quad = lane >> 4;
    // XCD swizzle over 512 items: it%8 -> gh%8
    int g8 = it & 7; int rest = it >> 3;
    int qt = rest & 15; int gh = (rest >> 4) * 8 + g8;
    int b = gh >> 1, h = gh & 1;

    // stage Q, pre-scaled by 1/sqrt(hd)=0.125 (exact exponent shift in bf16)
#pragma unroll
    for (int i = 0; i < 2; ++i) {
        int idx = t + i * 256;
        int r = idx >> 3, d8 = (idx & 7) * 8;
        size_t n = (size_t)b * SEQ + qt * 64 + r;
        float4 qv = *(const float4*)&qkv[n * QKVD + h * HDIM + d8];
        u16* qp = (u16*)&qv;
#pragma unroll
        for (int j = 0; j < 8; ++j) qp[j] = f2bf(bf2f(qp[j]) * 0.125f);
        *(float4*)&Qsh[r][d8] = qv;
    }
    int kr = t >> 3, kd8 = (t & 7) * 8;
    int vr = t & 63, vdb = (t >> 6) * 16;
    float4 kR[2], vR[2];
    {
        size_t nk0 = (size_t)b * SEQ + kr;
        kR[0] = *(const float4*)&qkv[nk0 * QKVD + DIM + h * HDIM + kd8];
        kR[1] = *(const float4*)&qkv[(nk0 + 32) * QKVD + DIM + h * HDIM + kd8];
        size_t nv0 = (size_t)b * SEQ + vr;
        vR[0] = *(const float4*)&qkv[nv0 * QKVD + 2 * DIM + h * HDIM + vdb];
        vR[1] = *(const float4*)&qkv[nv0 * QKVD + 2 * DIM + h * HDIM + vdb + 8];
    }
    __syncthreads();
    bf16x8 qa0 = *(const bf16x8*)&Qsh[w * 16 + l16][quad * 8];
    bf16x8 qa1 = *(const bf16x8*)&Qsh[w * 16 + l16][32 + quad * 8];

    f32x4 o[4] = {};
    float mrow[4] = {-1e30f, -1e30f, -1e30f, -1e30f};
    float lrow[4] = {};

#pragma unroll 1
    for (int kt = 0; kt < SEQ / 64; ++kt) {
        *(float4*)&Ksh[kr][kd8]      = kR[0];
        *(float4*)&Ksh[kr + 32][kd8] = kR[1];
        {
            const u16* pa = (const u16*)&vR[0];
            const u16* pb = (const u16*)&vR[1];
#pragma unroll
            for (int j = 0; j < 8; ++j) VshT[vdb + j][vr] = pa[j];
#pragma unroll
            for (int j = 0; j < 8; ++j) VshT[vdb + 8 + j][vr] = pb[j];
        }
        __syncthreads();
        if (kt + 1 < SEQ / 64) {
            size_t nk0 = (size_t)b * SEQ + (kt + 1) * 64 + kr;
            kR[0] = *(const float4*)&qkv[nk0 * QKVD + DIM + h * HDIM + kd8];
            kR[1] = *(const float4*)&qkv[(nk0 + 32) * QKVD + DIM + h * HDIM + kd8];
            size_t nv0 = (size_t)b * SEQ + (kt + 1) * 64 + vr;
            vR[0] = *(const float4*)&qkv[nv0 * QKVD + 2 * DIM + h * HDIM + vdb];
            vR[1] = *(const float4*)&qkv[nv0 * QKVD + 2 * DIM + h * HDIM + vdb + 8];
        }
        float sc[4][4];
        __builtin_amdgcn_s_setprio(1);
#pragma unroll
        for (int c = 0; c < 4; ++c) {
            bf16x8 kb0 = *(const bf16x8*)&Ksh[c * 16 + l16][quad * 8];
            bf16x8 kb1 = *(const bf16x8*)&Ksh[c * 16 + l16][32 + quad * 8];
            f32x4 s = {};
            s = __builtin_amdgcn_mfma_f32_16x16x32_bf16(qa0, kb0, s, 0, 0, 0);
            s = __builtin_amdgcn_mfma_f32_16x16x32_bf16(qa1, kb1, s, 0, 0, 0);
#pragma unroll
            for (int r = 0; r < 4; ++r) sc[c][r] = s[r];
        }
        __builtin_amdgcn_s_setprio(0);
        float alpha[4];
#pragma unroll
        for (int r = 0; r < 4; ++r) {
            float mx = fmaxf(fmaxf(sc[0][r], sc[1][r]), fmaxf(sc[2][r], sc[3][r]));
            mx = row16_max(mx);
            float mnew = fmaxf(mrow[r], mx);
            alpha[r] = __expf(mrow[r] - mnew);
            mrow[r] = mnew;
            float sum = 0.f;
#pragma unroll
            for (int c = 0; c < 4; ++c) {
                float p = __expf(sc[c][r] - mnew);
                sc[c][r] = p;
                sum += p;
            }
            sum = row16_sum(sum);
            lrow[r] = lrow[r] * alpha[r] + sum;
        }
#pragma unroll
        for (int c = 0; c < 4; ++c)
#pragma unroll
            for (int r = 0; r < 4; ++r)
                Psh[w * 16 + quad * 4 + r][c * 16 + l16] = f2bf(sc[c][r]);
#pragma unroll
        for (int dt = 0; dt < 4; ++dt)
#pragma unroll
            for (int r = 0; r < 4; ++r) o[dt][r] *= alpha[r];
        bf16x8 pa0 = *(const bf16x8*)&Psh[w * 16 + l16][quad * 8];
        bf16x8 pa1 = *(const bf16x8*)&Psh[w * 16 + l16][32 + quad * 8];
        __builtin_amdgcn_s_setprio(1);
#pragma unroll
        for (int dt = 0; dt < 4; ++dt) {
            bf16x8 vb0 = *(const bf16x8*)&VshT[dt * 16 + l16][quad * 8];
            bf16x8 vb1 = *(const bf16x8*)&VshT[dt * 16 + l16][32 + quad * 8];
            o[dt] = __builtin_amdgcn_mfma_f32_16x16x32_bf16(pa0, vb0, o[dt], 0, 0, 0);
            o[dt] = __builtin_amdgcn_mfma_f32_16x16x32_bf16(pa1, vb1, o[dt], 0, 0, 0);
        }
        __builtin_amdgcn_s_setprio(0);
        __syncthreads();
    }
#pragma unroll
    for (int r = 0; r < 4; ++r) {
        float inv = 1.f / lrow[r];
        size_t n = (size_t)b * SEQ + qt * 64 + w * 16 + quad * 4 + r;
#pragma unroll
        for (int dt = 0; dt < 4; ++dt)
            ctx[n * DIM + h * HDIM + dt * 16 + l16] = f2bf(o[dt][r] * inv);
    }
}

// ---- the fused cooperative kernel ------------------------------------------
__global__ __launch_bounds__(256)
void fused_layer(FArgs a)
{
    __shared__ __align__(16) char smem[SMEM_BYTES];
    cg::grid_group grid = cg::this_grid();
    int bid = blockIdx.x, G = gridDim.x, t = threadIdx.x;

    // phase -1: dtype detect (block 0)
    if (bid == 0 && t == 0) {
        const u16* xp = (const u16*)a.x;
        int ok = 1;
        for (int i = 0; i < 256; i += 2) {
            unsigned e = (xp[i] >> 7) & 0xFF;
            if (e < 60u || e > 180u) ok = 0;
        }
        *a.flag = ok;
    }
    grid.sync();
    int fbf = *a.flag;
    int rs  = fbf ? 128 : 256;

    // phase 0: pe  (h0 = x + pos @ pe_w^T + pe_b)
    {
        float (*wsh)[KPOS + 1] = (float(*)[KPOS + 1])smem;
        for (int i = t; i < DIM * KPOS; i += 256)
            wsh[i / KPOS][i % KPOS] = ld1(a.pe_w, fbf, i);
        __syncthreads();
        for (int it = bid; it < NTOT / 2; it += G) {
            int row = it * 2 + (t >> 7), d = t & 127;
            float acc = 0.f;
#pragma unroll
            for (int k = 0; k < KPOS; ++k)
                acc += ld1(a.pos, fbf, (size_t)row * KPOS + k) * wsh[d][k];
            a.h01[(size_t)row * rs + d] =
                f2bf(ld1(a.x, fbf, (size_t)row * DIM + d) + acc + ld1(a.pe_b, fbf, d));
        }
    }
    grid.sync();

    // phase 1: qkv = h0 @ in_w^T + in_b   (768 tiles of 64x128)
    for (int it = bid; it < 768; it += G)
        gemm_tile<0, 1>(a.h01, a.in_w, a.in_b, nullptr, nullptr, nullptr,
                        a.qkv, QKVD, rs, 0, 0,
                        (it & 255) * 64, (it >> 8) * 128, fbf, rs, smem);
    grid.sync();

    // phase 2: attention (512 items)
    for (int it = bid; it < 512; it += G)
        attn_tile(a.qkv, a.ctx, it, smem);
    grid.sync();

    // phase 3: h1 = LN1(h0 + ctx @ out_w^T + out_b)   (256 tiles)
    for (int it = bid; it < 256; it += G)
        gemm_tile<2, 1>(a.ctx, a.out_w, a.out_b, a.h01, a.ln1_g, a.ln1_b,
                        a.h01, DIM, DIM, 0, 0, it * 64, 0, fbf, rs, smem);
    grid.sync();

    // phase 4: f1 = relu(h1 @ ff1_w^T + ff1_b)   (1024 tiles)
    for (int it = bid; it < 1024; it += G)
        gemm_tile<1, 1>(a.h01, a.ff1_w, a.ff1_b, nullptr, nullptr, nullptr,
                        a.f1, 4 * DIM, rs, 0, 0,
                        (it & 255) * 64, (it >> 8) * 128, fbf, rs, smem);
    grid.sync();

    // phase 5: out = LN2(h1 + f1 @ ff2_w^T + ff2_b)   (256 tiles, K=512)
    for (int it = bid; it < 256; it += G)
        gemm_tile<3, 4>(a.f1, a.ff2_w, a.ff2_b, a.h01, a.ln2_g, a.ln2_b,
                        a.dout, DIM, 4 * DIM, 0, 0, it * 64, 0, fbf, rs, smem);
}

// ============================================================================
//                 LEGACY MULTI-KERNEL PATH (fallback + per-graph)
// ============================================================================

__global__ void detect_kernel(const u16* __restrict__ x, int* __restrict__ flag) {
    if (threadIdx.x == 0 && blockIdx.x == 0) {
        int ok = 1;
        for (int i = 0; i < 256; i += 2) {
            unsigned e = (x[i] >> 7) & 0xFF;
            if (e < 60u || e > 180u) ok = 0;
        }
        *flag = ok;
    }
}

__global__ __launch_bounds__(256)
void pe_kernel(const void* __restrict__ x, const void* __restrict__ pos,
               const void* __restrict__ pe_w, const void* __restrict__ pe_b,
               u16* __restrict__ h0, const int* __restrict__ flag) {
    int fbf = *flag;
    __shared__ float wsh[DIM][KPOS + 1];
    int t = threadIdx.x;
    for (int i = t; i < DIM * KPOS; i += 256)
        wsh[i / KPOS][i % KPOS] = ld1(pe_w, fbf, i);
    __syncthreads();
    int row = blockIdx.x * 2 + (t >> 7), d = t & 127;
    float acc = 0.f;
#pragma unroll
    for (int k = 0; k < KPOS; ++k)
        acc += ld1(pos, fbf, (size_t)row * KPOS + k) * wsh[d][k];
    int rs = fbf ? 128 : 256;
    h0[(size_t)row * rs + d] =
        f2bf(ld1(x, fbf, (size_t)row * DIM + d) + acc + ld1(pe_b, fbf, d));
}

template<int EPI, int NK>
__global__ __launch_bounds__(256)
void mgemm_kernel(const u16* __restrict__ A, const void* __restrict__ W,
                  const void* __restrict__ bias, const u16* __restrict__ resid,
                  const void* __restrict__ lng, const void* __restrict__ lnb,
                  void* __restrict__ outp, int Mtot, int AstrIn,
                  int arow0, int orow0, const int* __restrict__ flag) {
    const int K = NK * 128;
    int fbf  = *flag;
    int rs   = fbf ? 128 : 256;
    int Astr = (AstrIn < 0) ? rs : AstrIn;
    __shared__ u16 Ash[64][136];
    __shared__ u16 Wsh[128][136];
    int t = threadIdx.x;
    int w = t >> 6, lane = t & 63, l16 = lane & 15, quad = lane >> 4;
    int n0 = blockIdx.x * 64;
    int m0 = blockIdx.y * 128;
    f32x4 acc[8] = {};
    float4 aR[4], wR[8];
#pragma unroll
    for (int i = 0; i < 4; ++i) {
        int idx = t + i * 256;
        int row = idx >> 4, k8 = (idx & 15) * 8;
        aR[i] = *(const float4*)&A[(size_t)(arow0 + n0 + row) * Astr + k8];
    }
#pragma unroll
    for (int i = 0; i < 8; ++i) {
        int idx = t + i * 256;
        int row = idx >> 4, k8 = (idx & 15) * 8;
        wR[i] = ldw8(W, fbf, (size_t)(m0 + row) * K + k8);
    }
#pragma unroll 1
    for (int c = 0; c < NK; ++c) {
#pragma unroll
        for (int i = 0; i < 4; ++i) {
            int idx = t + i * 256;
            *(float4*)&Ash[idx >> 4][(idx & 15) * 8] = aR[i];
        }
#pragma unroll
        for (int i = 0; i < 8; ++i) {
            int idx = t + i * 256;
            *(float4*)&Wsh[idx >> 4][(idx & 15) * 8] = wR[i];
        }
        __syncthreads();
        if (c + 1 < NK) {
            int kc = (c + 1) * 128;
#pragma unroll
            for (int i = 0; i < 4; ++i) {
                int idx = t + i * 256;
                int row = idx >> 4, k8 = (idx & 15) * 8;
                aR[i] = *(const float4*)&A[(size_t)(arow0 + n0 + row) * Astr + kc + k8];
            }
#pragma unroll
            for (int i = 0; i < 8; ++i) {
                int idx = t + i * 256;
                int row = idx >> 4, k8 = (idx & 15) * 8;
                wR[i] = ldw8(W, fbf, (size_t)(m0 + row) * K + kc + k8);
            }
        }
#pragma unroll
        for (int kk = 0; kk < 4; ++kk) {
            bf16x8 af = *(const bf16x8*)&Ash[w * 16 + l16][kk * 32 + quad * 8];
#pragma unroll
            for (int s = 0; s < 8; ++s) {
                bf16x8 bf = *(const bf16x8*)&Wsh[s * 16 + l16][kk * 32 + quad * 8];
                acc[s] = __builtin_amdgcn_mfma_f32_16x16x32_bf16(af, bf, acc[s], 0, 0, 0);
            }
        }
        if (c + 1 < NK) __syncthreads();
    }
    float bb[8];
#pragma unroll
    for (int s = 0; s < 8; ++s) bb[s] = ld1(bias, fbf, m0 + s * 16 + l16);
    float gg[8], be[8];
    if (EPI >= 2) {
#pragma unroll
        for (int s = 0; s < 8; ++s) {
            gg[s] = ld1(lng, fbf, s * 16 + l16);
            be[s] = ld1(lnb, fbf, s * 16 + l16);
        }
    }
#pragma unroll
    for (int r = 0; r < 4; ++r) {
        int lr = w * 16 + quad * 4 + r;
        float v[8];
#pragma unroll
        for (int s = 0; s < 8; ++s) {
            v[s] = acc[s][r] + bb[s];
            if (EPI == 1) v[s] = fmaxf(v[s], 0.f);
        }
        if (EPI <= 1) {
            u16* o = (u16*)outp;
#pragma unroll
            for (int s = 0; s < 8; ++s)
                o[(size_t)(n0 + lr) * Mtot + m0 + s * 16 + l16] = f2bf(v[s]);
        } else {
            size_t rg = (size_t)(orow0 + n0 + lr);
#pragma unroll
            for (int s = 0; s < 8; ++s)
                v[s] += bf2f(resid[rg * rs + s * 16 + l16]);
            float sm = 0.f, sq = 0.f;
#pragma unroll
            for (int s = 0; s < 8; ++s) { sm += v[s]; sq += v[s] * v[s]; }
            sm = row16_sum(sm);
            sq = row16_sum(sq);
            float mu  = sm * (1.f / DIM);
            float var = fmaxf(sq * (1.f / DIM) - mu * mu, 0.f);
            float rsq = rsqrtf(var + 1e-5f);
            if (EPI == 2) {
                u16* o = (u16*)outp;
#pragma unroll
                for (int s = 0; s < 8; ++s)
                    o[rg * rs + s * 16 + l16] =
                        f2bf((v[s] - mu) * rsq * gg[s] + be[s]);
            } else {
                if (fbf) {
                    u16* o = (u16*)outp;
#pragma unroll
                    for (int s = 0; s < 8; ++s)
                        o[rg * 128 + s * 16 + l16] =
                            f2bf((v[s] - mu) * rsq * gg[s] + be[s]);
                } else {
                    float* o = (float*)outp;
#pragma unroll
                    for (int s = 0; s < 8; ++s)
                        o[rg * 128 + s * 16 + l16] =
                            (v[s] - mu) * rsq * gg[s] + be[s];
                }
            }
        }
    }
}

__global__ __launch_bounds__(256)
void attn_kernel(const u16* __restrict__ qkv, u16* __restrict__ ctx) {
    __shared__ __align__(16) char smem[SMEM_BYTES];
    int L = blockIdx.x;
    int ngh = gridDim.x >> 4;
    int it;
    if (ngh >= 8) {
        it = L;                       // attn_tile applies the swizzle
    } else {
        // per-graph path: no swizzle; build it so attn_tile's unswizzle
        // reproduces qt = L & 15, gh = L >> 4
        int qt = L & 15, gh = L >> 4;
        it = ((gh >> 3) * 16 + qt) * 8 + (gh & 7);
    }
    attn_tile(qkv, ctx, it, smem);
}

// ---------------------------------------------------------------------------
extern "C" void kernel_launch(void* const* d_in, const int* in_sizes, int n_in,
                              void* d_out, int out_size, void* d_ws, size_t ws_size,
                              hipStream_t stream) {
    const void* x     = d_in[0];
    const void* pos   = d_in[1];
    const void* pe_w  = d_in[2];
    const void* pe_b  = d_in[3];
    const void* in_w  = d_in[4];
    const void* in_b  = d_in[5];
    const void* out_w = d_in[6];
    const void* out_b = d_in[7];
    const void* ln1_g = d_in[8];
    const void* ln1_b = d_in[9];
    const void* ln2_g = d_in[10];
    const void* ln2_b = d_in[11];
    const void* ff1_w = d_in[12];
    const void* ff1_b = d_in[13];
    const void* ff2_w = d_in[14];
    const void* ff2_b = d_in[15];

    char* wsb  = (char*)d_ws;
    int*  flag = (int*)(wsb + ((ws_size - 4) & ~(size_t)3));
    u16*  h01  = (u16*)d_out;
    const size_t MB = 1024 * 1024;

    if (ws_size >= 17 * MB) {
        u16* qkv = (u16*)wsb;
        u16* ctx = (u16*)(wsb + 12 * MB);
        u16* f1  = (u16*)wsb;

        // ---- fused cooperative path ----
        FArgs fa;
        fa.x = x; fa.pos = pos; fa.pe_w = pe_w; fa.pe_b = pe_b;
        fa.in_w = in_w; fa.in_b = in_b; fa.out_w = out_w; fa.out_b = out_b;
        fa.ln1_g = ln1_g; fa.ln1_b = ln1_b; fa.ln2_g = ln2_g; fa.ln2_b = ln2_b;
        fa.ff1_w = ff1_w; fa.ff1_b = ff1_b; fa.ff2_w = ff2_w; fa.ff2_b = ff2_b;
        fa.h01 = h01; fa.qkv = qkv; fa.ctx = ctx; fa.f1 = f1;
        fa.dout = d_out; fa.flag = flag;

        int maxB = 0;
        hipError_t oe = hipOccupancyMaxActiveBlocksPerMultiprocessor(
            &maxB, (const void*)fused_layer, 256, 0);
        int G = (oe == hipSuccess) ? maxB * 256 : 0;
        if (G > 1024) G = 1024;
        if (G >= 256) {
            void* params[] = { (void*)&fa };
            hipError_t e = hipLaunchCooperativeKernel(
                (const void*)fused_layer, dim3(G), dim3(256), params, 0, stream);
            if (e == hipSuccess) return;
        }

        // ---- fallback: legacy multi-kernel pipeline ----
        detect_kernel<<<1, 1, 0, stream>>>((const u16*)x, flag);
        pe_kernel<<<NTOT / 2, 256, 0, stream>>>(x, pos, pe_w, pe_b, h01, flag);
        mgemm_kernel<0,1><<<dim3(NTOT / 64, 3), 256, 0, stream>>>(
            h01, in_w, in_b, nullptr, nullptr, nullptr, qkv,
            QKVD, -1, 0, 0, flag);
        attn_kernel<<<NGRAPH * NHEAD * 16, 256, 0, stream>>>(qkv, ctx);
        mgemm_kernel<2,1><<<dim3(NTOT / 64, 1), 256, 0, stream>>>(
            ctx, out_w, out_b, h01, ln1_g, ln1_b, h01,
            DIM, DIM, 0, 0, flag);
        mgemm_kernel<1,1><<<dim3(NTOT / 64, 4), 256, 0, stream>>>(
            h01, ff1_w, ff1_b, nullptr, nullptr, nullptr, f1,
            4 * DIM, -1, 0, 0, flag);
        mgemm_kernel<3,4><<<dim3(NTOT / 64, 1), 256, 0, stream>>>(
            f1, ff2_w, ff2_b, h01, ln2_g, ln2_b, d_out,
            DIM, 4 * DIM, 0, 0, flag);
    } else {
        // per-graph path: qkv_g[0,768K), ctx_g[768K,1M); f1_g reuses [0,1M)
        u16* qkv_g = (u16*)wsb;
        u16* ctx_g = (u16*)(wsb + 768 * 1024);
        u16* f1_g  = (u16*)wsb;
        detect_kernel<<<1, 1, 0, stream>>>((const u16*)x, flag);
        pe_kernel<<<NTOT / 2, 256, 0, stream>>>(x, pos, pe_w, pe_b, h01, flag);
        for (int g = 0; g < NGRAPH; ++g) {
            int row0 = g * SEQ;
            mgemm_kernel<0,1><<<dim3(SEQ / 64, 3), 256, 0, stream>>>(
                h01, in_w, in_b, nullptr, nullptr, nullptr, qkv_g,
                QKVD, -1, row0, 0, flag);
            attn_kernel<<<NHEAD * 16, 256, 0, stream>>>(qkv_g, ctx_g);
            mgemm_kernel<2,1><<<dim3(SEQ / 64, 1), 256, 0, stream>>>(
                ctx_g, out_w, out_b, h01, ln1_g, ln1_b, h01,
                DIM, DIM, 0, row0, flag);
        }
        for (int g = 0; g < NGRAPH; ++g) {
            int row0 = g * SEQ;
            mgemm_kernel<1,1><<<dim3(SEQ / 64, 4), 256, 0, stream>>>(
                h01, ff1_w, ff1_b, nullptr, nullptr, nullptr, f1_g,
                4 * DIM, -1, row0, 0, flag);
            mgemm_kernel<3,4><<<dim3(SEQ / 64, 1), 256, 0, stream>>>(
                f1_g, ff2_w, ff2_b, h01, ln2_g, ln2_b, d_out,
                DIM, 4 * DIM, 0, row0, flag);
        }
    }
}

// Round 4
// 225.973 us; speedup vs baseline: 1.9807x; 1.9807x over previous
//
#include <hip/hip_runtime.h>

typedef unsigned short u16;

#define NGRAPH 16
#define SEQ    1024
#define DIM    128
#define NHEAD  2
#define HDIM   64
#define KPOS   20
#define NTOT   (NGRAPH*SEQ)     // 16384
#define QKVD   (3*DIM)          // 384

// ---------- bf16 helpers ----------------------------------------------------
__device__ __forceinline__ float bf2f(u16 u) {
    return __uint_as_float(((unsigned int)u) << 16);
}
__device__ __forceinline__ u16 f2bf(float f) {
    unsigned int u = __float_as_uint(f);
    u += 0x7fffu + ((u >> 16) & 1u);   // RNE
    return (u16)(u >> 16);
}

// ---------- DPP 16-lane reductions (VALU, keeps DS pipe free) --------------
template<int CTRL>
__device__ __forceinline__ float dpp_ror(float x) {
    return __int_as_float(__builtin_amdgcn_update_dpp(
        __float_as_int(x), __float_as_int(x), CTRL, 0xF, 0xF, true));
}
__device__ __forceinline__ float row16_max(float x) {
    x = fmaxf(x, dpp_ror<0x121>(x));
    x = fmaxf(x, dpp_ror<0x122>(x));
    x = fmaxf(x, dpp_ror<0x124>(x));
    x = fmaxf(x, dpp_ror<0x128>(x));
    return x;
}
__device__ __forceinline__ float row16_sum(float x) {
    x += dpp_ror<0x121>(x);
    x += dpp_ror<0x122>(x);
    x += dpp_ror<0x124>(x);
    x += dpp_ror<0x128>(x);
    return x;
}

// ---------- dtype-adaptive input loads (fbf=1: bf16, fbf=0: f32) -----------
__device__ __forceinline__ float ld1(const void* p, int fbf, size_t i) {
    return fbf ? bf2f(((const u16*)p)[i]) : ((const float*)p)[i];
}
__device__ __forceinline__ float4 ldw8(const void* W, int fbf, size_t i) {
    if (fbf) return *(const float4*)((const u16*)W + i);
    const float* q = (const float*)W + i;
    float4 a = *(const float4*)q, b = *(const float4*)(q + 4);
    float4 r;
    u16* d = (u16*)&r;
    d[0]=f2bf(a.x); d[1]=f2bf(a.y); d[2]=f2bf(a.z); d[3]=f2bf(a.w);
    d[4]=f2bf(b.x); d[5]=f2bf(b.y); d[6]=f2bf(b.z); d[7]=f2bf(b.w);
    return r;
}

typedef __attribute__((ext_vector_type(8))) short bf16x8;
typedef __attribute__((ext_vector_type(4))) float f32x4;

// ---------- K0: dtype detection --------------------------------------------
__global__ void detect_kernel(const u16* __restrict__ x, int* __restrict__ flag) {
    if (threadIdx.x == 0 && blockIdx.x == 0) {
        int ok = 1;
        for (int i = 0; i < 256; i += 2) {
            unsigned e = (x[i] >> 7) & 0xFF;
            if (e < 60u || e > 180u) ok = 0;
        }
        *flag = ok;
    }
}

// ---------- K0b: one-time weight conversion to bf16 ------------------------
// All 4 GEMM weights -> contiguous bf16 buffer. Inputs are f32 (fbf=0) in
// practice: per-block re-conversion inside the GEMMs was ~192 VALU/thread per
// K-chunk plus 2x fetch bytes. Totals: in_w 49152 | out_w 16384 | ff1 65536 |
// ff2 65536 = 196608 elems. Grid 96 x 256 x 8 elems.
__global__ __launch_bounds__(256)
void wconv_kernel(const void* __restrict__ in_w, const void* __restrict__ out_w,
                  const void* __restrict__ ff1_w, const void* __restrict__ ff2_w,
                  u16* __restrict__ wbf, const int* __restrict__ flag) {
    int fbf = *flag;
    int i8 = (blockIdx.x * 256 + threadIdx.x) * 8;
    const void* src; int off;
    if      (i8 <  49152) { src = in_w;  off = i8; }
    else if (i8 <  65536) { src = out_w; off = i8 - 49152; }
    else if (i8 < 131072) { src = ff1_w; off = i8 - 65536; }
    else                  { src = ff2_w; off = i8 - 131072; }
    *(float4*)&wbf[i8] = ldw8(src, fbf, off);
}

// ---------- K1: h0 = x + pos_enc @ pe_w.T + pe_b  (bf16, strided slots) ----
__global__ __launch_bounds__(256)
void pe_kernel(const void* __restrict__ x, const void* __restrict__ pos,
               const void* __restrict__ pe_w, const void* __restrict__ pe_b,
               u16* __restrict__ h0, const int* __restrict__ flag) {
    int fbf = *flag;
    __shared__ float wsh[DIM][KPOS + 1];
    int t = threadIdx.x;
    for (int i = t; i < DIM * KPOS; i += 256)
        wsh[i / KPOS][i % KPOS] = ld1(pe_w, fbf, i);
    __syncthreads();
    int row = blockIdx.x * 2 + (t >> 7), d = t & 127;
    float acc = 0.f;
#pragma unroll
    for (int k = 0; k < KPOS; ++k)
        acc += ld1(pos, fbf, (size_t)row * KPOS + k) * wsh[d][k];
    int rs = fbf ? 128 : 256;   // h0 row slot stride (u16 units)
    h0[(size_t)row * rs + d] =
        f2bf(ld1(x, fbf, (size_t)row * DIM + d) + acc + ld1(pe_b, fbf, d));
}

// ---------- unified MFMA GEMM: out = A @ W^T (+epilogue) -------------------
// Block 256 = 4 waves; tile 64 rows x 128 cols; K staged 128 at a time,
// register-prefetched, one barrier per chunk.
// EPI 0: +bias -> bf16 ws (vt!=nullptr && m0==256: store V^T to vt instead)
// EPI 1: +bias,relu    EPI 2: +bias+resid+LN -> h01   EPI 3: same -> final
// wbf16=1: W is pre-converted bf16; wbf16=0: W format follows fbf.
template<int EPI, int NK>
__global__ __launch_bounds__(256)
void mgemm_kernel(const u16* __restrict__ A, const void* __restrict__ W,
                  int wbf16, const void* __restrict__ bias,
                  const u16* __restrict__ resid,
                  const void* __restrict__ lng, const void* __restrict__ lnb,
                  void* __restrict__ outp, u16* __restrict__ vt,
                  int Mtot, int AstrIn,
                  int arow0, int orow0, const int* __restrict__ flag) {
    const int K = NK * 128;
    int fbf  = *flag;
    int wfmt = wbf16 ? 1 : fbf;
    int rs   = fbf ? 128 : 256;
    int Astr = (AstrIn < 0) ? rs : AstrIn;
    __shared__ u16 Ash[64][136];    // [row][k] (+8 pad)
    __shared__ u16 Wsh[128][136];   // [col][k]
    int t = threadIdx.x;
    int w = t >> 6, lane = t & 63, l16 = lane & 15, quad = lane >> 4;
    int n0 = blockIdx.x * 64;
    int m0 = blockIdx.y * 128;
    f32x4 acc[8] = {};
    float4 aR[4], wR[8];
#pragma unroll
    for (int i = 0; i < 4; ++i) {
        int idx = t + i * 256;
        int row = idx >> 4, k8 = (idx & 15) * 8;
        aR[i] = *(const float4*)&A[(size_t)(arow0 + n0 + row) * Astr + k8];
    }
#pragma unroll
    for (int i = 0; i < 8; ++i) {
        int idx = t + i * 256;
        int row = idx >> 4, k8 = (idx & 15) * 8;
        wR[i] = ldw8(W, wfmt, (size_t)(m0 + row) * K + k8);
    }
#pragma unroll 1
    for (int c = 0; c < NK; ++c) {
#pragma unroll
        for (int i = 0; i < 4; ++i) {
            int idx = t + i * 256;
            *(float4*)&Ash[idx >> 4][(idx & 15) * 8] = aR[i];
        }
#pragma unroll
        for (int i = 0; i < 8; ++i) {
            int idx = t + i * 256;
            *(float4*)&Wsh[idx >> 4][(idx & 15) * 8] = wR[i];
        }
        __syncthreads();
        if (c + 1 < NK) {   // prefetch next chunk (overlaps MFMA below)
            int kc = (c + 1) * 128;
#pragma unroll
            for (int i = 0; i < 4; ++i) {
                int idx = t + i * 256;
                int row = idx >> 4, k8 = (idx & 15) * 8;
                aR[i] = *(const float4*)&A[(size_t)(arow0 + n0 + row) * Astr + kc + k8];
            }
#pragma unroll
            for (int i = 0; i < 8; ++i) {
                int idx = t + i * 256;
                int row = idx >> 4, k8 = (idx & 15) * 8;
                wR[i] = ldw8(W, wfmt, (size_t)(m0 + row) * K + kc + k8);
            }
        }
        __builtin_amdgcn_s_setprio(1);
#pragma unroll
        for (int kk = 0; kk < 4; ++kk) {
            bf16x8 af = *(const bf16x8*)&Ash[w * 16 + l16][kk * 32 + quad * 8];
#pragma unroll
            for (int s = 0; s < 8; ++s) {
                bf16x8 bf = *(const bf16x8*)&Wsh[s * 16 + l16][kk * 32 + quad * 8];
                acc[s] = __builtin_amdgcn_mfma_f32_16x16x32_bf16(af, bf, acc[s], 0, 0, 0);
            }
        }
        __builtin_amdgcn_s_setprio(0);
        if (c + 1 < NK) __syncthreads();
    }
    // ---- epilogue ----
    float bb[8];
#pragma unroll
    for (int s = 0; s < 8; ++s) bb[s] = ld1(bias, fbf, m0 + s * 16 + l16);
    float gg[8], be[8];
    if (EPI >= 2) {
#pragma unroll
        for (int s = 0; s < 8; ++s) {
            gg[s] = ld1(lng, fbf, s * 16 + l16);
            be[s] = ld1(lnb, fbf, s * 16 + l16);
        }
    }
#pragma unroll
    for (int r = 0; r < 4; ++r) {
        int lr = w * 16 + quad * 4 + r;
        float v[8];
#pragma unroll
        for (int s = 0; s < 8; ++s) {
            v[s] = acc[s][r] + bb[s];
            if (EPI == 1) v[s] = fmaxf(v[s], 0.f);
        }
        if (EPI <= 1) {
            if (EPI == 0 && vt != nullptr && m0 == 256) {
                // V-section of qkv: store transposed vt[(b*128+d)*SEQ + n]
                int n = n0 + lr;
                int bg = n >> 10, nl = n & 1023;
#pragma unroll
                for (int s = 0; s < 8; ++s)
                    vt[((size_t)(bg * 128) + s * 16 + l16) * SEQ + nl] = f2bf(v[s]);
            } else {
                u16* o = (u16*)outp;
#pragma unroll
                for (int s = 0; s < 8; ++s)
                    o[(size_t)(n0 + lr) * Mtot + m0 + s * 16 + l16] = f2bf(v[s]);
            }
        } else {
            size_t rg = (size_t)(orow0 + n0 + lr);
#pragma unroll
            for (int s = 0; s < 8; ++s)
                v[s] += bf2f(resid[rg * rs + s * 16 + l16]);
            float sm = 0.f, sq = 0.f;
#pragma unroll
            for (int s = 0; s < 8; ++s) { sm += v[s]; sq += v[s] * v[s]; }
            sm = row16_sum(sm);
            sq = row16_sum(sq);
            float mu  = sm * (1.f / DIM);
            float var = fmaxf(sq * (1.f / DIM) - mu * mu, 0.f);
            float rsq = rsqrtf(var + 1e-5f);
            if (EPI == 2) {
                u16* o = (u16*)outp;
#pragma unroll
                for (int s = 0; s < 8; ++s)
                    o[rg * rs + s * 16 + l16] =
                        f2bf((v[s] - mu) * rsq * gg[s] + be[s]);
            } else {
                if (fbf) {
                    u16* o = (u16*)outp;
#pragma unroll
                    for (int s = 0; s < 8; ++s)
                        o[rg * 128 + s * 16 + l16] =
                            f2bf((v[s] - mu) * rsq * gg[s] + be[s]);
                } else {
                    float* o = (float*)outp;
#pragma unroll
                    for (int s = 0; s < 8; ++s)
                        o[rg * 128 + s * 16 + l16] =
                            (v[s] - mu) * rsq * gg[s] + be[s];
                }
            }
        }
    }
}

// ---------- K3a: barrier-free direct-L2 flash attention (batched path) -----
// R3 lesson: attn was DS-staging bound (~66 DS ops/wave/tile, 4 waves on one
// LDS pipe). Here: 1 wave per block (grid = 32 gh x 64 wave-tiles = 2048),
// K fragments read directly from qkv and V fragments directly from vt
// (V^T written by the QKV GEMM). Each dwordx4's 64 lanes cover exactly 16
// full 64B lines (quads tile the line) -> efficient L2 gather; per-XCD
// working set ~1 MB via the gh%8 swizzle. LDS holds only the wave-private
// P tile (2.3 KB) -> ZERO __syncthreads; V-load latency hides under softmax.
__global__ __launch_bounds__(64)
void attn_direct_kernel(const u16* __restrict__ qkv,
                        const u16* __restrict__ vtp,
                        u16* __restrict__ ctx) {
    __shared__ u16 Psh[16][72];
    int lane = threadIdx.x & 63;
    int l16 = lane & 15, quad = lane >> 4;
    int L = blockIdx.x;
    int ngw = gridDim.x >> 6;
    int wt, gh;
    if (ngw >= 8) {           // XCD swizzle: L%8 -> gh%8
        int g8 = L & 7; int rest = L >> 3;
        wt = rest & 63; gh = (rest >> 6) * 8 + g8;
    } else {
        wt = L & 63; gh = L >> 6;
    }
    int b = gh >> 1, h = gh & 1;
    int q0 = wt * 16;

    // Q fragments (wave-private), pre-scaled by 0.125 (exact exponent shift)
    size_t qrow = (size_t)(b * SEQ + q0 + l16) * QKVD + h * HDIM;
    float4 qv0 = *(const float4*)&qkv[qrow + quad * 8];
    float4 qv1 = *(const float4*)&qkv[qrow + 32 + quad * 8];
    {
        u16* p = (u16*)&qv0;
#pragma unroll
        for (int j = 0; j < 8; ++j) p[j] = f2bf(bf2f(p[j]) * 0.125f);
        p = (u16*)&qv1;
#pragma unroll
        for (int j = 0; j < 8; ++j) p[j] = f2bf(bf2f(p[j]) * 0.125f);
    }
    bf16x8 qa0 = *(const bf16x8*)&qv0;
    bf16x8 qa1 = *(const bf16x8*)&qv1;

    const u16* kbase = qkv + (size_t)b * SEQ * QKVD + DIM + h * HDIM;
    const u16* vbase = vtp + (size_t)((b * 2 + h) * 64) * SEQ;

    f32x4 o[4] = {};
    float mrow[4] = {-1e30f, -1e30f, -1e30f, -1e30f};
    float lrow[4] = {};

#pragma unroll 1
    for (int kt = 0; kt < SEQ / 64; ++kt) {
        // issue all K and V gathers up front (V waits resolve under softmax)
        float4 kv[8], vv[8];
#pragma unroll
        for (int c = 0; c < 4; ++c) {
            const u16* kr = kbase + (size_t)(kt * 64 + c * 16 + l16) * QKVD;
            kv[c * 2]     = *(const float4*)&kr[quad * 8];
            kv[c * 2 + 1] = *(const float4*)&kr[32 + quad * 8];
        }
#pragma unroll
        for (int dt = 0; dt < 4; ++dt) {
            const u16* vr = vbase + (size_t)(dt * 16 + l16) * SEQ + kt * 64;
            vv[dt * 2]     = *(const float4*)&vr[quad * 8];
            vv[dt * 2 + 1] = *(const float4*)&vr[32 + quad * 8];
        }
        float sc[4][4];
        __builtin_amdgcn_s_setprio(1);
#pragma unroll
        for (int c = 0; c < 4; ++c) {
            f32x4 s = {};
            s = __builtin_amdgcn_mfma_f32_16x16x32_bf16(
                    qa0, *(const bf16x8*)&kv[c * 2], s, 0, 0, 0);
            s = __builtin_amdgcn_mfma_f32_16x16x32_bf16(
                    qa1, *(const bf16x8*)&kv[c * 2 + 1], s, 0, 0, 0);
#pragma unroll
            for (int r = 0; r < 4; ++r) sc[c][r] = s[r];
        }
        __builtin_amdgcn_s_setprio(0);
        float alpha[4];
#pragma unroll
        for (int r = 0; r < 4; ++r) {
            float mx = fmaxf(fmaxf(sc[0][r], sc[1][r]), fmaxf(sc[2][r], sc[3][r]));
            mx = row16_max(mx);
            float mnew = fmaxf(mrow[r], mx);
            alpha[r] = __expf(mrow[r] - mnew);
            mrow[r] = mnew;
            float sum = 0.f;
#pragma unroll
            for (int c = 0; c < 4; ++c) {
                float p = __expf(sc[c][r] - mnew);
                sc[c][r] = p;
                sum += p;
            }
            sum = row16_sum(sum);
            lrow[r] = lrow[r] * alpha[r] + sum;
        }
#pragma unroll
        for (int c = 0; c < 4; ++c)
#pragma unroll
            for (int r = 0; r < 4; ++r)
                Psh[quad * 4 + r][c * 16 + l16] = f2bf(sc[c][r]);
#pragma unroll
        for (int dt = 0; dt < 4; ++dt)
#pragma unroll
            for (int r = 0; r < 4; ++r) o[dt][r] *= alpha[r];
        bf16x8 pa0 = *(const bf16x8*)&Psh[l16][quad * 8];
        bf16x8 pa1 = *(const bf16x8*)&Psh[l16][32 + quad * 8];
        __builtin_amdgcn_s_setprio(1);
#pragma unroll
        for (int dt = 0; dt < 4; ++dt) {
            o[dt] = __builtin_amdgcn_mfma_f32_16x16x32_bf16(
                        pa0, *(const bf16x8*)&vv[dt * 2], o[dt], 0, 0, 0);
            o[dt] = __builtin_amdgcn_mfma_f32_16x16x32_bf16(
                        pa1, *(const bf16x8*)&vv[dt * 2 + 1], o[dt], 0, 0, 0);
        }
        __builtin_amdgcn_s_setprio(0);
    }
#pragma unroll
    for (int r = 0; r < 4; ++r) {
        float inv = 1.f / lrow[r];
        size_t n = (size_t)b * SEQ + q0 + quad * 4 + r;
#pragma unroll
        for (int dt = 0; dt < 4; ++dt)
            ctx[n * DIM + h * HDIM + dt * 16 + l16] = f2bf(o[dt][r] * inv);
    }
}

// ---------- K3b: legacy LDS-staged attention (per-graph fallback) ----------
__global__ __launch_bounds__(256)
void attn_lds_kernel(const u16* __restrict__ qkv, u16* __restrict__ ctx) {
    __shared__ u16 Qsh[64][72];
    __shared__ u16 Ksh[64][72];
    __shared__ u16 VshT[64][72];
    __shared__ u16 Psh[64][72];
    int t    = threadIdx.x;
    int w    = t >> 6;
    int lane = t & 63;
    int l16  = lane & 15;
    int quad = lane >> 4;
    int L = blockIdx.x;
    int qt = L & 15, gh = L >> 4;
    int b = gh >> 1, h = gh & 1;

#pragma unroll
    for (int i = 0; i < 2; ++i) {
        int idx = t + i * 256;
        int r = idx >> 3, d8 = (idx & 7) * 8;
        size_t n = (size_t)b * SEQ + qt * 64 + r;
        float4 qv = *(const float4*)&qkv[n * QKVD + h * HDIM + d8];
        u16* qp = (u16*)&qv;
#pragma unroll
        for (int j = 0; j < 8; ++j) qp[j] = f2bf(bf2f(qp[j]) * 0.125f);
        *(float4*)&Qsh[r][d8] = qv;
    }
    int kr = t >> 3, kd8 = (t & 7) * 8;
    int vr = t & 63, vdb = (t >> 6) * 16;
    float4 kR[2], vR[2];
    {
        size_t nk0 = (size_t)b * SEQ + kr;
        kR[0] = *(const float4*)&qkv[nk0 * QKVD + DIM + h * HDIM + kd8];
        kR[1] = *(const float4*)&qkv[(nk0 + 32) * QKVD + DIM + h * HDIM + kd8];
        size_t nv0 = (size_t)b * SEQ + vr;
        vR[0] = *(const float4*)&qkv[nv0 * QKVD + 2 * DIM + h * HDIM + vdb];
        vR[1] = *(const float4*)&qkv[nv0 * QKVD + 2 * DIM + h * HDIM + vdb + 8];
    }
    __syncthreads();
    bf16x8 qa0 = *(const bf16x8*)&Qsh[w * 16 + l16][quad * 8];
    bf16x8 qa1 = *(const bf16x8*)&Qsh[w * 16 + l16][32 + quad * 8];

    f32x4 o[4] = {};
    float mrow[4] = {-1e30f, -1e30f, -1e30f, -1e30f};
    float lrow[4] = {};

#pragma unroll 1
    for (int kt = 0; kt < SEQ / 64; ++kt) {
        *(float4*)&Ksh[kr][kd8]      = kR[0];
        *(float4*)&Ksh[kr + 32][kd8] = kR[1];
        {
            const u16* pa = (const u16*)&vR[0];
            const u16* pb = (const u16*)&vR[1];
#pragma unroll
            for (int j = 0; j < 8; ++j) VshT[vdb + j][vr] = pa[j];
#pragma unroll
            for (int j = 0; j < 8; ++j) VshT[vdb + 8 + j][vr] = pb[j];
        }
        __syncthreads();
        if (kt + 1 < SEQ / 64) {
            size_t nk0 = (size_t)b * SEQ + (kt + 1) * 64 + kr;
            kR[0] = *(const float4*)&qkv[nk0 * QKVD + DIM + h * HDIM + kd8];
            kR[1] = *(const float4*)&qkv[(nk0 + 32) * QKVD + DIM + h * HDIM + kd8];
            size_t nv0 = (size_t)b * SEQ + (kt + 1) * 64 + vr;
            vR[0] = *(const float4*)&qkv[nv0 * QKVD + 2 * DIM + h * HDIM + vdb];
            vR[1] = *(const float4*)&qkv[nv0 * QKVD + 2 * DIM + h * HDIM + vdb + 8];
        }
        float sc[4][4];
        __builtin_amdgcn_s_setprio(1);
#pragma unroll
        for (int c = 0; c < 4; ++c) {
            bf16x8 kb0 = *(const bf16x8*)&Ksh[c * 16 + l16][quad * 8];
            bf16x8 kb1 = *(const bf16x8*)&Ksh[c * 16 + l16][32 + quad * 8];
            f32x4 s = {};
            s = __builtin_amdgcn_mfma_f32_16x16x32_bf16(qa0, kb0, s, 0, 0, 0);
            s = __builtin_amdgcn_mfma_f32_16x16x32_bf16(qa1, kb1, s, 0, 0, 0);
#pragma unroll
            for (int r = 0; r < 4; ++r) sc[c][r] = s[r];
        }
        __builtin_amdgcn_s_setprio(0);
        float alpha[4];
#pragma unroll
        for (int r = 0; r < 4; ++r) {
            float mx = fmaxf(fmaxf(sc[0][r], sc[1][r]), fmaxf(sc[2][r], sc[3][r]));
            mx = row16_max(mx);
            float mnew = fmaxf(mrow[r], mx);
            alpha[r] = __expf(mrow[r] - mnew);
            mrow[r] = mnew;
            float sum = 0.f;
#pragma unroll
            for (int c = 0; c < 4; ++c) {
                float p = __expf(sc[c][r] - mnew);
                sc[c][r] = p;
                sum += p;
            }
            sum = row16_sum(sum);
            lrow[r] = lrow[r] * alpha[r] + sum;
        }
#pragma unroll
        for (int c = 0; c < 4; ++c)
#pragma unroll
            for (int r = 0; r < 4; ++r)
                Psh[w * 16 + quad * 4 + r][c * 16 + l16] = f2bf(sc[c][r]);
#pragma unroll
        for (int dt = 0; dt < 4; ++dt)
#pragma unroll
            for (int r = 0; r < 4; ++r) o[dt][r] *= alpha[r];
        bf16x8 pa0 = *(const bf16x8*)&Psh[w * 16 + l16][quad * 8];
        bf16x8 pa1 = *(const bf16x8*)&Psh[w * 16 + l16][32 + quad * 8];
        __builtin_amdgcn_s_setprio(1);
#pragma unroll
        for (int dt = 0; dt < 4; ++dt) {
            bf16x8 vb0 = *(const bf16x8*)&VshT[dt * 16 + l16][quad * 8];
            bf16x8 vb1 = *(const bf16x8*)&VshT[dt * 16 + l16][32 + quad * 8];
            o[dt] = __builtin_amdgcn_mfma_f32_16x16x32_bf16(pa0, vb0, o[dt], 0, 0, 0);
            o[dt] = __builtin_amdgcn_mfma_f32_16x16x32_bf16(pa1, vb1, o[dt], 0, 0, 0);
        }
        __builtin_amdgcn_s_setprio(0);
        __syncthreads();
    }
#pragma unroll
    for (int r = 0; r < 4; ++r) {
        float inv = 1.f / lrow[r];
        size_t n = (size_t)b * SEQ + qt * 64 + w * 16 + quad * 4 + r;
#pragma unroll
        for (int dt = 0; dt < 4; ++dt)
            ctx[n * DIM + h * HDIM + dt * 16 + l16] = f2bf(o[dt][r] * inv);
    }
}

// ---------------------------------------------------------------------------
extern "C" void kernel_launch(void* const* d_in, const int* in_sizes, int n_in,
                              void* d_out, int out_size, void* d_ws, size_t ws_size,
                              hipStream_t stream) {
    const void* x     = d_in[0];
    const void* pos   = d_in[1];
    const void* pe_w  = d_in[2];
    const void* pe_b  = d_in[3];
    const void* in_w  = d_in[4];
    const void* in_b  = d_in[5];
    const void* out_w = d_in[6];
    const void* out_b = d_in[7];
    const void* ln1_g = d_in[8];
    const void* ln1_b = d_in[9];
    const void* ln2_g = d_in[10];
    const void* ln2_b = d_in[11];
    const void* ff1_w = d_in[12];
    const void* ff1_b = d_in[13];
    const void* ff2_w = d_in[14];
    const void* ff2_b = d_in[15];

    char* wsb  = (char*)d_ws;
    int*  flag = (int*)(wsb + ((ws_size - 4) & ~(size_t)3));
    u16*  h01  = (u16*)d_out;   // h0 then h1, bf16 in dtype-dependent row slots
    const size_t MB = 1024 * 1024;

    detect_kernel<<<1, 1, 0, stream>>>((const u16*)x, flag);

    if (ws_size >= 21 * MB) {
        // batched path: qkv[0,12M), ctx[12,16M), f1 reuses [0,16M),
        // vt[16,20M), wbf[20M,20M+384K)
        u16* qkv = (u16*)wsb;
        u16* ctx = (u16*)(wsb + 12 * MB);
        u16* f1  = (u16*)wsb;
        u16* vt  = (u16*)(wsb + 16 * MB);
        u16* wbf = (u16*)(wsb + 20 * MB);
        u16* wb_in  = wbf;
        u16* wb_out = wbf + 49152;
        u16* wb_ff1 = wbf + 65536;
        u16* wb_ff2 = wbf + 131072;

        wconv_kernel<<<96, 256, 0, stream>>>(in_w, out_w, ff1_w, ff2_w, wbf, flag);
        pe_kernel<<<NTOT / 2, 256, 0, stream>>>(x, pos, pe_w, pe_b, h01, flag);
        mgemm_kernel<0,1><<<dim3(NTOT / 64, 3), 256, 0, stream>>>(
            h01, wb_in, 1, in_b, nullptr, nullptr, nullptr, qkv, vt,
            QKVD, -1, 0, 0, flag);
        attn_direct_kernel<<<NGRAPH * NHEAD * 64, 64, 0, stream>>>(qkv, vt, ctx);
        mgemm_kernel<2,1><<<dim3(NTOT / 64, 1), 256, 0, stream>>>(
            ctx, wb_out, 1, out_b, h01, ln1_g, ln1_b, h01, nullptr,
            DIM, DIM, 0, 0, flag);
        mgemm_kernel<1,1><<<dim3(NTOT / 64, 4), 256, 0, stream>>>(
            h01, wb_ff1, 1, ff1_b, nullptr, nullptr, nullptr, f1, nullptr,
            4 * DIM, -1, 0, 0, flag);
        mgemm_kernel<3,4><<<dim3(NTOT / 64, 1), 256, 0, stream>>>(
            f1, wb_ff2, 1, ff2_b, h01, ln2_g, ln2_b, d_out, nullptr,
            DIM, 4 * DIM, 0, 0, flag);
    } else {
        // per-graph path: qkv_g[0,768K), ctx_g[768K,1M); f1_g reuses [0,1M)
        u16* qkv_g = (u16*)wsb;
        u16* ctx_g = (u16*)(wsb + 768 * 1024);
        u16* f1_g  = (u16*)wsb;
        pe_kernel<<<NTOT / 2, 256, 0, stream>>>(x, pos, pe_w, pe_b, h01, flag);
        for (int g = 0; g < NGRAPH; ++g) {
            int row0 = g * SEQ;
            mgemm_kernel<0,1><<<dim3(SEQ / 64, 3), 256, 0, stream>>>(
                h01, in_w, 0, in_b, nullptr, nullptr, nullptr, qkv_g, nullptr,
                QKVD, -1, row0, 0, flag);
            attn_lds_kernel<<<NHEAD * 16, 256, 0, stream>>>(qkv_g, ctx_g);
            mgemm_kernel<2,1><<<dim3(SEQ / 64, 1), 256, 0, stream>>>(
                ctx_g, out_w, 0, out_b, h01, ln1_g, ln1_b, h01, nullptr,
                DIM, DIM, 0, row0, flag);
        }
        for (int g = 0; g < NGRAPH; ++g) {
            int row0 = g * SEQ;
            mgemm_kernel<1,1><<<dim3(SEQ / 64, 4), 256, 0, stream>>>(
                h01, ff1_w, 0, ff1_b, nullptr, nullptr, nullptr, f1_g, nullptr,
                4 * DIM, -1, row0, 0, flag);
            mgemm_kernel<3,4><<<dim3(SEQ / 64, 1), 256, 0, stream>>>(
                f1_g, ff2_w, 0, ff2_b, h01, ln2_g, ln2_b, d_out, nullptr,
                DIM, 4 * DIM, 0, row0, flag);
        }
    }
}

// Round 5
// 187.679 us; speedup vs baseline: 2.3848x; 1.2040x over previous
//
#include <hip/hip_runtime.h>

typedef unsigned short u16;

#define NGRAPH 16
#define SEQ    1024
#define DIM    128
#define NHEAD  2
#define HDIM   64
#define KPOS   20
#define NTOT   (NGRAPH*SEQ)     // 16384
#define QKVD   (3*DIM)          // 384

// ---------- bf16 helpers ----------------------------------------------------
__device__ __forceinline__ float bf2f(u16 u) {
    return __uint_as_float(((unsigned int)u) << 16);
}
__device__ __forceinline__ u16 f2bf(float f) {
    unsigned int u = __float_as_uint(f);
    u += 0x7fffu + ((u >> 16) & 1u);   // RNE
    return (u16)(u >> 16);
}

// ---------- DPP 16-lane reductions (VALU, keeps DS pipe free) --------------
template<int CTRL>
__device__ __forceinline__ float dpp_ror(float x) {
    return __int_as_float(__builtin_amdgcn_update_dpp(
        __float_as_int(x), __float_as_int(x), CTRL, 0xF, 0xF, true));
}
__device__ __forceinline__ float row16_max(float x) {
    x = fmaxf(x, dpp_ror<0x121>(x));
    x = fmaxf(x, dpp_ror<0x122>(x));
    x = fmaxf(x, dpp_ror<0x124>(x));
    x = fmaxf(x, dpp_ror<0x128>(x));
    return x;
}
__device__ __forceinline__ float row16_sum(float x) {
    x += dpp_ror<0x121>(x);
    x += dpp_ror<0x122>(x);
    x += dpp_ror<0x124>(x);
    x += dpp_ror<0x128>(x);
    return x;
}

// ---------- dtype-adaptive input loads (fbf=1: bf16, fbf=0: f32) -----------
__device__ __forceinline__ float ld1(const void* p, int fbf, size_t i) {
    return fbf ? bf2f(((const u16*)p)[i]) : ((const float*)p)[i];
}
__device__ __forceinline__ float4 ldw8(const void* W, int fbf, size_t i) {
    if (fbf) return *(const float4*)((const u16*)W + i);
    const float* q = (const float*)W + i;
    float4 a = *(const float4*)q, b = *(const float4*)(q + 4);
    float4 r;
    u16* d = (u16*)&r;
    d[0]=f2bf(a.x); d[1]=f2bf(a.y); d[2]=f2bf(a.z); d[3]=f2bf(a.w);
    d[4]=f2bf(b.x); d[5]=f2bf(b.y); d[6]=f2bf(b.z); d[7]=f2bf(b.w);
    return r;
}

typedef __attribute__((ext_vector_type(8))) short bf16x8;
typedef __attribute__((ext_vector_type(4))) float f32x4;

// ---------- direct global->LDS (width 16), per-lane global addr ------------
__device__ __forceinline__ void gload16(const u16* g, u16* l) {
    __builtin_amdgcn_global_load_lds(
        (const __attribute__((address_space(1))) unsigned int*)(g),
        (__attribute__((address_space(3))) unsigned int*)(l), 16, 0, 0);
}
#define VMCNT0() asm volatile("s_waitcnt vmcnt(0)" ::: "memory")

// ---------- dtype detect (host-callable kernel kept for per-graph path) ----
__device__ __forceinline__ int detect_bf16(const u16* x) {
    int ok = 1;
    for (int i = 0; i < 256; i += 2) {
        unsigned e = (x[i] >> 7) & 0xFF;
        if (e < 60u || e > 180u) ok = 0;
    }
    return ok;
}
__global__ void detect_kernel(const u16* __restrict__ x, int* __restrict__ flag) {
    if (threadIdx.x == 0 && blockIdx.x == 0) *flag = detect_bf16(x);
}

// ---------- K0: weight conversion to bf16 (+ self-detect, writes flag) -----
__global__ __launch_bounds__(256)
void wconv_kernel(const void* __restrict__ in_w, const void* __restrict__ out_w,
                  const void* __restrict__ ff1_w, const void* __restrict__ ff2_w,
                  const u16* __restrict__ x,
                  u16* __restrict__ wbf, int* __restrict__ flag) {
    __shared__ int fsh;
    if (threadIdx.x == 0) {
        int ok = detect_bf16(x);
        fsh = ok;
        if (blockIdx.x == 0) *flag = ok;
    }
    __syncthreads();
    int fbf = fsh;
    int i8 = (blockIdx.x * 256 + threadIdx.x) * 8;
    const void* src; int off;
    if      (i8 <  49152) { src = in_w;  off = i8; }
    else if (i8 <  65536) { src = out_w; off = i8 - 49152; }
    else if (i8 < 131072) { src = ff1_w; off = i8 - 65536; }
    else                  { src = ff2_w; off = i8 - 131072; }
    *(float4*)&wbf[i8] = ldw8(src, fbf, off);
}

// ---------- K1: h0 = x + pos_enc @ pe_w.T + pe_b  (bf16, strided slots) ----
__global__ __launch_bounds__(256)
void pe_kernel(const void* __restrict__ x, const void* __restrict__ pos,
               const void* __restrict__ pe_w, const void* __restrict__ pe_b,
               u16* __restrict__ h0, const int* __restrict__ flag) {
    int fbf = *flag;
    __shared__ float wsh[DIM][KPOS + 1];
    int t = threadIdx.x;
    for (int i = t; i < DIM * KPOS; i += 256)
        wsh[i / KPOS][i % KPOS] = ld1(pe_w, fbf, i);
    __syncthreads();
    int row = blockIdx.x * 2 + (t >> 7), d = t & 127;
    float acc = 0.f;
#pragma unroll
    for (int k = 0; k < KPOS; ++k)
        acc += ld1(pos, fbf, (size_t)row * KPOS + k) * wsh[d][k];
    int rs = fbf ? 128 : 256;   // h0 row slot stride (u16 units)
    h0[(size_t)row * rs + d] =
        f2bf(ld1(x, fbf, (size_t)row * DIM + d) + acc + ld1(pe_b, fbf, d));
}

// ===========================================================================
// K2 (batched): MFMA GEMM with global_load_lds staging + XOR swizzle.
// Block 256 = 4 waves; tile 64 rows x 128 cols; K in NK chunks of 128.
// LDS layout is UNPADDED (gload_lds requires linear dest); bank conflicts
// avoided by both-sides XOR swizzle (rule 21): per-lane GLOBAL source column
// slot is XOR'd by (row&7), reads XOR the same. NK>1 double-buffers.
// W must be bf16 (pre-converted). EPI semantics as before:
// 0:+bias (vt!=null&&m0==256 -> V^T to vt)  1:+bias,relu
// 2:+bias+resid+LN->h01 slots               3:+bias+resid+LN->final out
// ===========================================================================
template<int EPI, int NK>
__global__ __launch_bounds__(256)
void mgemm2_kernel(const u16* __restrict__ A, const u16* __restrict__ W,
                   const void* __restrict__ bias, const u16* __restrict__ resid,
                   const void* __restrict__ lng, const void* __restrict__ lnb,
                   void* __restrict__ outp, u16* __restrict__ vt,
                   int Mtot, int AstrIn,
                   int arow0, int orow0, const int* __restrict__ flag) {
    const int K  = NK * 128;
    const int NB = (NK > 1) ? 2 : 1;
    int fbf  = *flag;
    int rs   = fbf ? 128 : 256;
    int Astr = (AstrIn < 0) ? rs : AstrIn;
    __shared__ __align__(16) u16 Ash[NB][64][128];
    __shared__ __align__(16) u16 Wsh[NB][128][128];
    int t = threadIdx.x;
    int w = t >> 6, lane = t & 63, l16 = lane & 15, quad = lane >> 4;
    int n0 = blockIdx.x * 64;
    int m0 = blockIdx.y * 128;
    int xr = (l16 & 7) << 3;           // read-side XOR (u16 units)
    f32x4 acc[8] = {};

    auto stage = [&](int c, int b) {
        int kc = c * 128;
#pragma unroll
        for (int i = 0; i < 4; ++i) {              // A: 64 rows x 256B
            int r = w * 4 + i * 16 + (lane >> 4);
            int s = (lane & 15) ^ (r & 7);
            gload16(&A[(size_t)(arow0 + n0 + r) * Astr + kc + s * 8],
                    &Ash[b][w * 4 + i * 16][0]);
        }
#pragma unroll
        for (int i = 0; i < 8; ++i) {              // W: 128 rows x 256B
            int r = w * 4 + i * 16 + (lane >> 4);
            int s = (lane & 15) ^ (r & 7);
            gload16(&W[(size_t)(m0 + r) * K + kc + s * 8],
                    &Wsh[b][w * 4 + i * 16][0]);
        }
    };

    stage(0, 0);
#pragma unroll 1
    for (int c = 0; c < NK; ++c) {
        VMCNT0();
        __syncthreads();
        if (c + 1 < NK) stage(c + 1, (c + 1) & (NB - 1));
        int b = c & (NB - 1);
        __builtin_amdgcn_s_setprio(1);
#pragma unroll
        for (int kk = 0; kk < 4; ++kk) {
            bf16x8 af = *(const bf16x8*)&Ash[b][w * 16 + l16][(kk * 32 + quad * 8) ^ xr];
#pragma unroll
            for (int s = 0; s < 8; ++s) {
                bf16x8 bf = *(const bf16x8*)&Wsh[b][s * 16 + l16][(kk * 32 + quad * 8) ^ xr];
                acc[s] = __builtin_amdgcn_mfma_f32_16x16x32_bf16(af, bf, acc[s], 0, 0, 0);
            }
        }
        __builtin_amdgcn_s_setprio(0);
    }
    // ---- epilogue ----
    float bb[8];
#pragma unroll
    for (int s = 0; s < 8; ++s) bb[s] = ld1(bias, fbf, m0 + s * 16 + l16);
    float gg[8], be[8];
    if (EPI >= 2) {
#pragma unroll
        for (int s = 0; s < 8; ++s) {
            gg[s] = ld1(lng, fbf, s * 16 + l16);
            be[s] = ld1(lnb, fbf, s * 16 + l16);
        }
    }
#pragma unroll
    for (int r = 0; r < 4; ++r) {
        int lr = w * 16 + quad * 4 + r;
        float v[8];
#pragma unroll
        for (int s = 0; s < 8; ++s) {
            v[s] = acc[s][r] + bb[s];
            if (EPI == 1) v[s] = fmaxf(v[s], 0.f);
        }
        if (EPI <= 1) {
            if (EPI == 0 && vt != nullptr && m0 == 256) {
                // V-section of qkv: store transposed vt[(b*128+d)*SEQ + n]
                int n = n0 + lr;
                int bg = n >> 10, nl = n & 1023;
#pragma unroll
                for (int s = 0; s < 8; ++s)
                    vt[((size_t)(bg * 128) + s * 16 + l16) * SEQ + nl] = f2bf(v[s]);
            } else {
                u16* o = (u16*)outp;
#pragma unroll
                for (int s = 0; s < 8; ++s)
                    o[(size_t)(n0 + lr) * Mtot + m0 + s * 16 + l16] = f2bf(v[s]);
            }
        } else {
            size_t rg = (size_t)(orow0 + n0 + lr);
#pragma unroll
            for (int s = 0; s < 8; ++s)
                v[s] += bf2f(resid[rg * rs + s * 16 + l16]);
            float sm = 0.f, sq = 0.f;
#pragma unroll
            for (int s = 0; s < 8; ++s) { sm += v[s]; sq += v[s] * v[s]; }
            sm = row16_sum(sm);
            sq = row16_sum(sq);
            float mu  = sm * (1.f / DIM);
            float var = fmaxf(sq * (1.f / DIM) - mu * mu, 0.f);
            float rsq = rsqrtf(var + 1e-5f);
            if (EPI == 2) {
                u16* o = (u16*)outp;
#pragma unroll
                for (int s = 0; s < 8; ++s)
                    o[rg * rs + s * 16 + l16] =
                        f2bf((v[s] - mu) * rsq * gg[s] + be[s]);
            } else {
                if (fbf) {
                    u16* o = (u16*)outp;
#pragma unroll
                    for (int s = 0; s < 8; ++s)
                        o[rg * 128 + s * 16 + l16] =
                            f2bf((v[s] - mu) * rsq * gg[s] + be[s]);
                } else {
                    float* o = (float*)outp;
#pragma unroll
                    for (int s = 0; s < 8; ++s)
                        o[rg * 128 + s * 16 + l16] =
                            (v[s] - mu) * rsq * gg[s] + be[s];
                }
            }
        }
    }
}

// ===========================================================================
// K3 (batched): LDS flash attention, K/V staged via global_load_lds into
// XOR-swizzled double buffers. V arrives pre-transposed from vt (the QKV
// GEMM writes V^T), eliminating the 16-scalar-write LDS transpose that
// dominated the DS pipe (R4: conflicts 2.37M -> 262K when removed).
// Q staged once (padded, regular writes); P round-trip unchanged.
// ===========================================================================
__global__ __launch_bounds__(256)
void attn2_kernel(const u16* __restrict__ qkv, const u16* __restrict__ vtp,
                  u16* __restrict__ ctx) {
    __shared__ __align__(16) u16 Qsh[64][72];
    __shared__ __align__(16) u16 Ksh[2][64][64];
    __shared__ __align__(16) u16 Vsh[2][64][64];
    __shared__ u16 Psh[64][72];
    int t    = threadIdx.x;
    int w    = t >> 6;
    int lane = t & 63;
    int l16  = lane & 15;
    int quad = lane >> 4;
    int xr   = (l16 & 7) << 3;
    int L = blockIdx.x;
    int ngh = gridDim.x >> 4;
    int qt, gh;
    if (ngh >= 8) {           // XCD swizzle: L%8 selects XCD -> gh%8
        int g8 = L & 7; int rest = L >> 3;
        qt = rest & 15; gh = (rest >> 4) * 8 + g8;
    } else {
        qt = L & 15; gh = L >> 4;
    }
    int b = gh >> 1, h = gh & 1;

    // ---- stage Q, pre-scaled by 1/sqrt(hd)=0.125 (exact exponent shift) ----
#pragma unroll
    for (int i = 0; i < 2; ++i) {
        int idx = t + i * 256;
        int r = idx >> 3, d8 = (idx & 7) * 8;
        size_t n = (size_t)b * SEQ + qt * 64 + r;
        float4 qv = *(const float4*)&qkv[n * QKVD + h * HDIM + d8];
        u16* qp = (u16*)&qv;
#pragma unroll
        for (int j = 0; j < 8; ++j) qp[j] = f2bf(bf2f(qp[j]) * 0.125f);
        *(float4*)&Qsh[r][d8] = qv;
    }

    const u16* kbase = qkv + (size_t)b * SEQ * QKVD + DIM + h * HDIM;
    const u16* vbase = vtp + (size_t)((b * 2 + h) * 64) * SEQ;

    auto stageKV = [&](int kt, int bf) {
#pragma unroll
        for (int i = 0; i < 2; ++i) {          // K: 64 rows x 128B
            int r = w * 8 + i * 32 + (lane >> 3);
            int s = (lane & 7) ^ (r & 7);
            gload16(&kbase[(size_t)(kt * 64 + r) * QKVD + s * 8],
                    &Ksh[bf][w * 8 + i * 32][0]);
        }
#pragma unroll
        for (int i = 0; i < 2; ++i) {          // V^T: 64 d-rows x 128B window
            int r = w * 8 + i * 32 + (lane >> 3);
            int s = (lane & 7) ^ (r & 7);
            gload16(&vbase[(size_t)r * SEQ + kt * 64 + s * 8],
                    &Vsh[bf][w * 8 + i * 32][0]);
        }
    };

    stageKV(0, 0);
    VMCNT0();
    __syncthreads();
    bf16x8 qa0 = *(const bf16x8*)&Qsh[w * 16 + l16][quad * 8];
    bf16x8 qa1 = *(const bf16x8*)&Qsh[w * 16 + l16][32 + quad * 8];

    f32x4 o[4] = {};
    float mrow[4] = {-1e30f, -1e30f, -1e30f, -1e30f};
    float lrow[4] = {};

#pragma unroll 1
    for (int kt = 0; kt < SEQ / 64; ++kt) {
        int cur = kt & 1;
        if (kt + 1 < SEQ / 64) stageKV(kt + 1, cur ^ 1);  // flies under compute

        float sc[4][4];
        __builtin_amdgcn_s_setprio(1);
#pragma unroll
        for (int c = 0; c < 4; ++c) {
            bf16x8 kb0 = *(const bf16x8*)&Ksh[cur][c * 16 + l16][(quad * 8) ^ xr];
            bf16x8 kb1 = *(const bf16x8*)&Ksh[cur][c * 16 + l16][(32 + quad * 8) ^ xr];
            f32x4 s = {};
            s = __builtin_amdgcn_mfma_f32_16x16x32_bf16(qa0, kb0, s, 0, 0, 0);
            s = __builtin_amdgcn_mfma_f32_16x16x32_bf16(qa1, kb1, s, 0, 0, 0);
#pragma unroll
            for (int r = 0; r < 4; ++r) sc[c][r] = s[r];
        }
        __builtin_amdgcn_s_setprio(0);
        float alpha[4];
#pragma unroll
        for (int r = 0; r < 4; ++r) {
            float mx = fmaxf(fmaxf(sc[0][r], sc[1][r]), fmaxf(sc[2][r], sc[3][r]));
            mx = row16_max(mx);
            float mnew = fmaxf(mrow[r], mx);
            alpha[r] = __expf(mrow[r] - mnew);
            mrow[r] = mnew;
            float sum = 0.f;
#pragma unroll
            for (int c = 0; c < 4; ++c) {
                float p = __expf(sc[c][r] - mnew);
                sc[c][r] = p;
                sum += p;
            }
            sum = row16_sum(sum);
            lrow[r] = lrow[r] * alpha[r] + sum;
        }
#pragma unroll
        for (int c = 0; c < 4; ++c)
#pragma unroll
            for (int r = 0; r < 4; ++r)
                Psh[w * 16 + quad * 4 + r][c * 16 + l16] = f2bf(sc[c][r]);
#pragma unroll
        for (int dt = 0; dt < 4; ++dt)
#pragma unroll
            for (int r = 0; r < 4; ++r) o[dt][r] *= alpha[r];
        bf16x8 pa0 = *(const bf16x8*)&Psh[w * 16 + l16][quad * 8];
        bf16x8 pa1 = *(const bf16x8*)&Psh[w * 16 + l16][32 + quad * 8];
        __builtin_amdgcn_s_setprio(1);
#pragma unroll
        for (int dt = 0; dt < 4; ++dt) {
            bf16x8 vb0 = *(const bf16x8*)&Vsh[cur][dt * 16 + l16][(quad * 8) ^ xr];
            bf16x8 vb1 = *(const bf16x8*)&Vsh[cur][dt * 16 + l16][(32 + quad * 8) ^ xr];
            o[dt] = __builtin_amdgcn_mfma_f32_16x16x32_bf16(pa0, vb0, o[dt], 0, 0, 0);
            o[dt] = __builtin_amdgcn_mfma_f32_16x16x32_bf16(pa1, vb1, o[dt], 0, 0, 0);
        }
        __builtin_amdgcn_s_setprio(0);
        if (kt + 1 < SEQ / 64) {
            VMCNT0();          // next tile staged (had full compute to land)
            __syncthreads();
        }
    }
#pragma unroll
    for (int r = 0; r < 4; ++r) {
        float inv = 1.f / lrow[r];
        size_t n = (size_t)b * SEQ + qt * 64 + w * 16 + quad * 4 + r;
#pragma unroll
        for (int dt = 0; dt < 4; ++dt)
            ctx[n * DIM + h * HDIM + dt * 16 + l16] = f2bf(o[dt][r] * inv);
    }
}

// ============================================================================
//                 LEGACY KERNELS (per-graph fallback path)
// ============================================================================
template<int EPI, int NK>
__global__ __launch_bounds__(256)
void mgemm_kernel(const u16* __restrict__ A, const void* __restrict__ W,
                  int wbf16, const void* __restrict__ bias,
                  const u16* __restrict__ resid,
                  const void* __restrict__ lng, const void* __restrict__ lnb,
                  void* __restrict__ outp, u16* __restrict__ vt,
                  int Mtot, int AstrIn,
                  int arow0, int orow0, const int* __restrict__ flag) {
    const int K = NK * 128;
    int fbf  = *flag;
    int wfmt = wbf16 ? 1 : fbf;
    int rs   = fbf ? 128 : 256;
    int Astr = (AstrIn < 0) ? rs : AstrIn;
    __shared__ u16 Ash[64][136];
    __shared__ u16 Wsh[128][136];
    int t = threadIdx.x;
    int w = t >> 6, lane = t & 63, l16 = lane & 15, quad = lane >> 4;
    int n0 = blockIdx.x * 64;
    int m0 = blockIdx.y * 128;
    f32x4 acc[8] = {};
    float4 aR[4], wR[8];
#pragma unroll
    for (int i = 0; i < 4; ++i) {
        int idx = t + i * 256;
        int row = idx >> 4, k8 = (idx & 15) * 8;
        aR[i] = *(const float4*)&A[(size_t)(arow0 + n0 + row) * Astr + k8];
    }
#pragma unroll
    for (int i = 0; i < 8; ++i) {
        int idx = t + i * 256;
        int row = idx >> 4, k8 = (idx & 15) * 8;
        wR[i] = ldw8(W, wfmt, (size_t)(m0 + row) * K + k8);
    }
#pragma unroll 1
    for (int c = 0; c < NK; ++c) {
#pragma unroll
        for (int i = 0; i < 4; ++i) {
            int idx = t + i * 256;
            *(float4*)&Ash[idx >> 4][(idx & 15) * 8] = aR[i];
        }
#pragma unroll
        for (int i = 0; i < 8; ++i) {
            int idx = t + i * 256;
            *(float4*)&Wsh[idx >> 4][(idx & 15) * 8] = wR[i];
        }
        __syncthreads();
        if (c + 1 < NK) {
            int kc = (c + 1) * 128;
#pragma unroll
            for (int i = 0; i < 4; ++i) {
                int idx = t + i * 256;
                int row = idx >> 4, k8 = (idx & 15) * 8;
                aR[i] = *(const float4*)&A[(size_t)(arow0 + n0 + row) * Astr + kc + k8];
            }
#pragma unroll
            for (int i = 0; i < 8; ++i) {
                int idx = t + i * 256;
                int row = idx >> 4, k8 = (idx & 15) * 8;
                wR[i] = ldw8(W, wfmt, (size_t)(m0 + row) * K + kc + k8);
            }
        }
        __builtin_amdgcn_s_setprio(1);
#pragma unroll
        for (int kk = 0; kk < 4; ++kk) {
            bf16x8 af = *(const bf16x8*)&Ash[w * 16 + l16][kk * 32 + quad * 8];
#pragma unroll
            for (int s = 0; s < 8; ++s) {
                bf16x8 bf = *(const bf16x8*)&Wsh[s * 16 + l16][kk * 32 + quad * 8];
                acc[s] = __builtin_amdgcn_mfma_f32_16x16x32_bf16(af, bf, acc[s], 0, 0, 0);
            }
        }
        __builtin_amdgcn_s_setprio(0);
        if (c + 1 < NK) __syncthreads();
    }
    float bb[8];
#pragma unroll
    for (int s = 0; s < 8; ++s) bb[s] = ld1(bias, fbf, m0 + s * 16 + l16);
    float gg[8], be[8];
    if (EPI >= 2) {
#pragma unroll
        for (int s = 0; s < 8; ++s) {
            gg[s] = ld1(lng, fbf, s * 16 + l16);
            be[s] = ld1(lnb, fbf, s * 16 + l16);
        }
    }
#pragma unroll
    for (int r = 0; r < 4; ++r) {
        int lr = w * 16 + quad * 4 + r;
        float v[8];
#pragma unroll
        for (int s = 0; s < 8; ++s) {
            v[s] = acc[s][r] + bb[s];
            if (EPI == 1) v[s] = fmaxf(v[s], 0.f);
        }
        if (EPI <= 1) {
            u16* o = (u16*)outp;
#pragma unroll
            for (int s = 0; s < 8; ++s)
                o[(size_t)(n0 + lr) * Mtot + m0 + s * 16 + l16] = f2bf(v[s]);
        } else {
            size_t rg = (size_t)(orow0 + n0 + lr);
#pragma unroll
            for (int s = 0; s < 8; ++s)
                v[s] += bf2f(resid[rg * rs + s * 16 + l16]);
            float sm = 0.f, sq = 0.f;
#pragma unroll
            for (int s = 0; s < 8; ++s) { sm += v[s]; sq += v[s] * v[s]; }
            sm = row16_sum(sm);
            sq = row16_sum(sq);
            float mu  = sm * (1.f / DIM);
            float var = fmaxf(sq * (1.f / DIM) - mu * mu, 0.f);
            float rsq = rsqrtf(var + 1e-5f);
            if (EPI == 2) {
                u16* o = (u16*)outp;
#pragma unroll
                for (int s = 0; s < 8; ++s)
                    o[rg * rs + s * 16 + l16] =
                        f2bf((v[s] - mu) * rsq * gg[s] + be[s]);
            } else {
                if (fbf) {
                    u16* o = (u16*)outp;
#pragma unroll
                    for (int s = 0; s < 8; ++s)
                        o[rg * 128 + s * 16 + l16] =
                            f2bf((v[s] - mu) * rsq * gg[s] + be[s]);
                } else {
                    float* o = (float*)outp;
#pragma unroll
                    for (int s = 0; s < 8; ++s)
                        o[rg * 128 + s * 16 + l16] =
                            (v[s] - mu) * rsq * gg[s] + be[s];
                }
            }
        }
    }
}

__global__ __launch_bounds__(256)
void attn_lds_kernel(const u16* __restrict__ qkv, u16* __restrict__ ctx) {
    __shared__ u16 Qsh[64][72];
    __shared__ u16 Ksh[64][72];
    __shared__ u16 VshT[64][72];
    __shared__ u16 Psh[64][72];
    int t    = threadIdx.x;
    int w    = t >> 6;
    int lane = t & 63;
    int l16  = lane & 15;
    int quad = lane >> 4;
    int L = blockIdx.x;
    int qt = L & 15, gh = L >> 4;
    int b = gh >> 1, h = gh & 1;

#pragma unroll
    for (int i = 0; i < 2; ++i) {
        int idx = t + i * 256;
        int r = idx >> 3, d8 = (idx & 7) * 8;
        size_t n = (size_t)b * SEQ + qt * 64 + r;
        float4 qv = *(const float4*)&qkv[n * QKVD + h * HDIM + d8];
        u16* qp = (u16*)&qv;
#pragma unroll
        for (int j = 0; j < 8; ++j) qp[j] = f2bf(bf2f(qp[j]) * 0.125f);
        *(float4*)&Qsh[r][d8] = qv;
    }
    int kr = t >> 3, kd8 = (t & 7) * 8;
    int vr = t & 63, vdb = (t >> 6) * 16;
    float4 kR[2], vR[2];
    {
        size_t nk0 = (size_t)b * SEQ + kr;
        kR[0] = *(const float4*)&qkv[nk0 * QKVD + DIM + h * HDIM + kd8];
        kR[1] = *(const float4*)&qkv[(nk0 + 32) * QKVD + DIM + h * HDIM + kd8];
        size_t nv0 = (size_t)b * SEQ + vr;
        vR[0] = *(const float4*)&qkv[nv0 * QKVD + 2 * DIM + h * HDIM + vdb];
        vR[1] = *(const float4*)&qkv[nv0 * QKVD + 2 * DIM + h * HDIM + vdb + 8];
    }
    __syncthreads();
    bf16x8 qa0 = *(const bf16x8*)&Qsh[w * 16 + l16][quad * 8];
    bf16x8 qa1 = *(const bf16x8*)&Qsh[w * 16 + l16][32 + quad * 8];

    f32x4 o[4] = {};
    float mrow[4] = {-1e30f, -1e30f, -1e30f, -1e30f};
    float lrow[4] = {};

#pragma unroll 1
    for (int kt = 0; kt < SEQ / 64; ++kt) {
        *(float4*)&Ksh[kr][kd8]      = kR[0];
        *(float4*)&Ksh[kr + 32][kd8] = kR[1];
        {
            const u16* pa = (const u16*)&vR[0];
            const u16* pb = (const u16*)&vR[1];
#pragma unroll
            for (int j = 0; j < 8; ++j) VshT[vdb + j][vr] = pa[j];
#pragma unroll
            for (int j = 0; j < 8; ++j) VshT[vdb + 8 + j][vr] = pb[j];
        }
        __syncthreads();
        if (kt + 1 < SEQ / 64) {
            size_t nk0 = (size_t)b * SEQ + (kt + 1) * 64 + kr;
            kR[0] = *(const float4*)&qkv[nk0 * QKVD + DIM + h * HDIM + kd8];
            kR[1] = *(const float4*)&qkv[(nk0 + 32) * QKVD + DIM + h * HDIM + kd8];
            size_t nv0 = (size_t)b * SEQ + (kt + 1) * 64 + vr;
            vR[0] = *(const float4*)&qkv[nv0 * QKVD + 2 * DIM + h * HDIM + vdb];
            vR[1] = *(const float4*)&qkv[nv0 * QKVD + 2 * DIM + h * HDIM + vdb + 8];
        }
        float sc[4][4];
        __builtin_amdgcn_s_setprio(1);
#pragma unroll
        for (int c = 0; c < 4; ++c) {
            bf16x8 kb0 = *(const bf16x8*)&Ksh[c * 16 + l16][quad * 8];
            bf16x8 kb1 = *(const bf16x8*)&Ksh[c * 16 + l16][32 + quad * 8];
            f32x4 s = {};
            s = __builtin_amdgcn_mfma_f32_16x16x32_bf16(qa0, kb0, s, 0, 0, 0);
            s = __builtin_amdgcn_mfma_f32_16x16x32_bf16(qa1, kb1, s, 0, 0, 0);
#pragma unroll
            for (int r = 0; r < 4; ++r) sc[c][r] = s[r];
        }
        __builtin_amdgcn_s_setprio(0);
        float alpha[4];
#pragma unroll
        for (int r = 0; r < 4; ++r) {
            float mx = fmaxf(fmaxf(sc[0][r], sc[1][r]), fmaxf(sc[2][r], sc[3][r]));
            mx = row16_max(mx);
            float mnew = fmaxf(mrow[r], mx);
            alpha[r] = __expf(mrow[r] - mnew);
            mrow[r] = mnew;
            float sum = 0.f;
#pragma unroll
            for (int c = 0; c < 4; ++c) {
                float p = __expf(sc[c][r] - mnew);
                sc[c][r] = p;
                sum += p;
            }
            sum = row16_sum(sum);
            lrow[r] = lrow[r] * alpha[r] + sum;
        }
#pragma unroll
        for (int c = 0; c < 4; ++c)
#pragma unroll
            for (int r = 0; r < 4; ++r)
                Psh[w * 16 + quad * 4 + r][c * 16 + l16] = f2bf(sc[c][r]);
#pragma unroll
        for (int dt = 0; dt < 4; ++dt)
#pragma unroll
            for (int r = 0; r < 4; ++r) o[dt][r] *= alpha[r];
        bf16x8 pa0 = *(const bf16x8*)&Psh[w * 16 + l16][quad * 8];
        bf16x8 pa1 = *(const bf16x8*)&Psh[w * 16 + l16][32 + quad * 8];
        __builtin_amdgcn_s_setprio(1);
#pragma unroll
        for (int dt = 0; dt < 4; ++dt) {
            bf16x8 vb0 = *(const bf16x8*)&VshT[dt * 16 + l16][quad * 8];
            bf16x8 vb1 = *(const bf16x8*)&VshT[dt * 16 + l16][32 + quad * 8];
            o[dt] = __builtin_amdgcn_mfma_f32_16x16x32_bf16(pa0, vb0, o[dt], 0, 0, 0);
            o[dt] = __builtin_amdgcn_mfma_f32_16x16x32_bf16(pa1, vb1, o[dt], 0, 0, 0);
        }
        __builtin_amdgcn_s_setprio(0);
        __syncthreads();
    }
#pragma unroll
    for (int r = 0; r < 4; ++r) {
        float inv = 1.f / lrow[r];
        size_t n = (size_t)b * SEQ + qt * 64 + w * 16 + quad * 4 + r;
#pragma unroll
        for (int dt = 0; dt < 4; ++dt)
            ctx[n * DIM + h * HDIM + dt * 16 + l16] = f2bf(o[dt][r] * inv);
    }
}

// ---------------------------------------------------------------------------
extern "C" void kernel_launch(void* const* d_in, const int* in_sizes, int n_in,
                              void* d_out, int out_size, void* d_ws, size_t ws_size,
                              hipStream_t stream) {
    const void* x     = d_in[0];
    const void* pos   = d_in[1];
    const void* pe_w  = d_in[2];
    const void* pe_b  = d_in[3];
    const void* in_w  = d_in[4];
    const void* in_b  = d_in[5];
    const void* out_w = d_in[6];
    const void* out_b = d_in[7];
    const void* ln1_g = d_in[8];
    const void* ln1_b = d_in[9];
    const void* ln2_g = d_in[10];
    const void* ln2_b = d_in[11];
    const void* ff1_w = d_in[12];
    const void* ff1_b = d_in[13];
    const void* ff2_w = d_in[14];
    const void* ff2_b = d_in[15];

    char* wsb  = (char*)d_ws;
    int*  flag = (int*)(wsb + ((ws_size - 4) & ~(size_t)3));
    u16*  h01  = (u16*)d_out;   // h0 then h1, bf16 in dtype-dependent row slots
    const size_t MB = 1024 * 1024;

    if (ws_size >= 21 * MB) {
        // batched path: qkv[0,12M), ctx[12,16M), f1 reuses [0,16M),
        // vt[16,20M), wbf[20M,20M+384K)
        u16* qkv = (u16*)wsb;
        u16* ctx = (u16*)(wsb + 12 * MB);
        u16* f1  = (u16*)wsb;
        u16* vt  = (u16*)(wsb + 16 * MB);
        u16* wbf = (u16*)(wsb + 20 * MB);
        u16* wb_in  = wbf;
        u16* wb_out = wbf + 49152;
        u16* wb_ff1 = wbf + 65536;
        u16* wb_ff2 = wbf + 131072;

        wconv_kernel<<<96, 256, 0, stream>>>(in_w, out_w, ff1_w, ff2_w,
                                             (const u16*)x, wbf, flag);
        pe_kernel<<<NTOT / 2, 256, 0, stream>>>(x, pos, pe_w, pe_b, h01, flag);
        mgemm2_kernel<0,1><<<dim3(NTOT / 64, 3), 256, 0, stream>>>(
            h01, wb_in, in_b, nullptr, nullptr, nullptr, qkv, vt,
            QKVD, -1, 0, 0, flag);
        attn2_kernel<<<NGRAPH * NHEAD * 16, 256, 0, stream>>>(qkv, vt, ctx);
        mgemm2_kernel<2,1><<<dim3(NTOT / 64, 1), 256, 0, stream>>>(
            ctx, wb_out, out_b, h01, ln1_g, ln1_b, h01, nullptr,
            DIM, DIM, 0, 0, flag);
        mgemm2_kernel<1,1><<<dim3(NTOT / 64, 4), 256, 0, stream>>>(
            h01, wb_ff1, ff1_b, nullptr, nullptr, nullptr, f1, nullptr,
            4 * DIM, -1, 0, 0, flag);
        mgemm2_kernel<3,4><<<dim3(NTOT / 64, 1), 256, 0, stream>>>(
            f1, wb_ff2, ff2_b, h01, ln2_g, ln2_b, d_out, nullptr,
            DIM, 4 * DIM, 0, 0, flag);
    } else {
        // per-graph path (legacy): qkv_g[0,768K), ctx_g[768K,1M); f1_g reuse
        u16* qkv_g = (u16*)wsb;
        u16* ctx_g = (u16*)(wsb + 768 * 1024);
        u16* f1_g  = (u16*)wsb;
        detect_kernel<<<1, 1, 0, stream>>>((const u16*)x, flag);
        pe_kernel<<<NTOT / 2, 256, 0, stream>>>(x, pos, pe_w, pe_b, h01, flag);
        for (int g = 0; g < NGRAPH; ++g) {
            int row0 = g * SEQ;
            mgemm_kernel<0,1><<<dim3(SEQ / 64, 3), 256, 0, stream>>>(
                h01, in_w, 0, in_b, nullptr, nullptr, nullptr, qkv_g, nullptr,
                QKVD, -1, row0, 0, flag);
            attn_lds_kernel<<<NHEAD * 16, 256, 0, stream>>>(qkv_g, ctx_g);
            mgemm_kernel<2,1><<<dim3(SEQ / 64, 1), 256, 0, stream>>>(
                ctx_g, out_w, 0, out_b, h01, ln1_g, ln1_b, h01, nullptr,
                DIM, DIM, 0, row0, flag);
        }
        for (int g = 0; g < NGRAPH; ++g) {
            int row0 = g * SEQ;
            mgemm_kernel<1,1><<<dim3(SEQ / 64, 4), 256, 0, stream>>>(
                h01, ff1_w, 0, ff1_b, nullptr, nullptr, nullptr, f1_g, nullptr,
                4 * DIM, -1, row0, 0, flag);
            mgemm_kernel<3,4><<<dim3(SEQ / 64, 1), 256, 0, stream>>>(
                f1_g, ff2_w, 0, ff2_b, h01, ln2_g, ln2_b, d_out, nullptr,
                DIM, 4 * DIM, 0, row0, flag);
        }
    }
}